// Round 8
// baseline (326.312 us; speedup 1.0000x reference)
//
#include <hip/hip_runtime.h>

#define NTOK   131072
#define KCODES 1024
#define DIM    64
#define BM     128
#define BN     64
#define NCT    (KCODES / BN)         // 16 code tiles
#define BSTR   288                   // Bs row stride (bytes), !=0 mod 128
#define BUFSZ  (64 * BSTR)           // 18432 B per Bs buffer

#define LOSS_OFF (NTOK * DIM)        // 8388608
#define IDX_OFF  (LOSS_OFF + 1)      // 8388609

#define EPS_U 6e-5f                  // u-metric gap threshold (d-gap = 2u)

typedef __attribute__((ext_vector_type(8))) short bf16x8;
typedef __attribute__((ext_vector_type(4))) float f32x4;
typedef __attribute__((ext_vector_type(4))) unsigned short ush4;

__device__ inline unsigned short bf16rtn(float x) {
    unsigned u = __float_as_uint(x);
    return (unsigned short)((u + 0x7fffu + ((u >> 16) & 1u)) >> 16);
}

// -------------------- K0: split E -> bf16 hi|lo, esq(+half), clear cnt
__global__ __launch_bounds__(256) void prep_kernel(const float* __restrict__ E,
                                                   unsigned short* __restrict__ B,
                                                   float* __restrict__ esq,
                                                   float* __restrict__ esqh,
                                                   int* __restrict__ cnt) {
    const int t = threadIdx.x, b = blockIdx.x;
    if (b == 0 && t == 0) cnt[0] = 0;
    int id = b * 256 + t;                      // 65536 = 1024 x 64
    int c = id >> 6, k = id & 63;
    float x = E[id];
    unsigned short h = bf16rtn(x);
    float hf = __uint_as_float(((unsigned)h) << 16);
    unsigned short lo = bf16rtn(x - hf);
    B[c * 128 + k]      = h;
    B[c * 128 + 64 + k] = lo;
    if (b < 4) {                               // esq: arithmetic verbatim (R1-R7)
        int cc = b * 256 + t;
        const float4* row = (const float4*)(E + cc * DIM);
        float s = 0.f;
        #pragma unroll
        for (int i = 0; i < DIM / 4; ++i) {
            float4 v = row[i];
            s += v.x * v.x + v.y * v.y + v.z * v.z + v.w * v.w;
        }
        esq[cc] = s;
        esqh[cc] = 0.5f * s;                   // exact
    }
}

// ------------------------------------------------- K1: MFMA distances + argmin
// 512 threads = 8 waves (4 row-groups x 2 col-groups); wave tile 32 tok x 32
// codes; 16 code tiles of BN=64. K=192 bf16 (hh,hl,lh). A frags preloaded to
// regs; As LDS (32KB) is then DEAD -> overlaid with double-buffered Bs
// (2 x 18KB, row stride 288B kills staging-write bank conflicts). One barrier
// per code tile. u = esq/2 - dot; (best,second,idx); near-ties -> worklist.
__global__ __launch_bounds__(512, 6) void mfma_argmin_kernel(
    const float* __restrict__ z, const unsigned short* __restrict__ Bsp,
    const float* __restrict__ esqh_g, float* __restrict__ idx_out,
    int* __restrict__ cnt, int* __restrict__ wl) {
    __shared__ __align__(16) char lds[2 * BUFSZ];        // 36KB: As(32KB)/Bs dbuf
    __shared__ __align__(16) float esqh_s[KCODES];       // 4KB
    __shared__ float cb_best[2][BM];                     // 1KB
    __shared__ float cb_sec[2][BM];                      // 1KB
    __shared__ int   cb_idx[2][BM];                      // 1KB

    const int t = threadIdx.x;
    const int l = t & 63;
    const int w = t >> 6;            // wave 0..7
    const int rg = w >> 1;           // row group (32 tokens)
    const int cg = w & 1;            // col group (32 codes)
    const int lan15 = l & 15;
    const int kp16 = (l >> 4) * 16;  // k-group byte offset within fragment
    const int xr = (lan15 & 7) << 4; // bank-swizzle XOR (row%8 == lan15%8)
    const int row0 = blockIdx.x * BM;

    // stage esq_half
    #pragma unroll
    for (int p = 0; p < 2; ++p) esqh_s[p * 512 + t] = esqh_g[p * 512 + t];

    // ---- prologue: load z tile + B tile 0 ----
    float4 av[4];
    {
        const float4* zg = (const float4*)(z + (size_t)row0 * DIM);
        #pragma unroll
        for (int p = 0; p < 4; ++p) av[p] = zg[p * 512 + t];
    }
    uint4 pv[2];
    {
        const uint4* bg = (const uint4*)Bsp;
        #pragma unroll
        for (int p = 0; p < 2; ++p) pv[p] = bg[p * 512 + t];
    }
    // convert/write A into overlay region (stride 256B, rows 0..127)
    #pragma unroll
    for (int p = 0; p < 4; ++p) {
        int li = p * 512 + t;
        int r = li >> 4, q = li & 15;          // token row, float4 chunk
        float xs[4] = {av[p].x, av[p].y, av[p].z, av[p].w};
        ush4 hv, lv;
        #pragma unroll
        for (int j = 0; j < 4; ++j) {
            unsigned short h = bf16rtn(xs[j]);
            float hf = __uint_as_float(((unsigned)h) << 16);
            hv[j] = h;
            lv[j] = bf16rtn(xs[j] - hf);
        }
        int rx = (r & 7) << 4;
        *(ush4*)(lds + r * 256 + ((q * 8) ^ rx))       = hv;
        *(ush4*)(lds + r * 256 + ((128 + q * 8) ^ rx)) = lv;
    }
    __syncthreads();

    // k-offsets for the 4 64B quarters (hi k0-31, hi k32-63, lo k0-31, lo k32-63)
    int kofs[4];
    #pragma unroll
    for (int j = 0; j < 4; ++j) kofs[j] = (j * 64 + kp16) ^ xr;

    // A fragments are code-tile invariant: preload all 2fr x 4j into regs
    {
        const char* ab = lds + (rg * 32 + lan15) * 256;
        // (read below, then As is dead)
        bf16x8 a00 = *(const bf16x8*)(ab + kofs[0]);
        bf16x8 a01 = *(const bf16x8*)(ab + kofs[1]);
        bf16x8 a02 = *(const bf16x8*)(ab + kofs[2]);
        bf16x8 a03 = *(const bf16x8*)(ab + kofs[3]);
        bf16x8 a10 = *(const bf16x8*)(ab + 4096 + kofs[0]);
        bf16x8 a11 = *(const bf16x8*)(ab + 4096 + kofs[1]);
        bf16x8 a12 = *(const bf16x8*)(ab + 4096 + kofs[2]);
        bf16x8 a13 = *(const bf16x8*)(ab + 4096 + kofs[3]);
        __syncthreads();             // all waves done reading As -> overlay free

        // write B tile 0 into buf0 (stride 288B)
        #pragma unroll
        for (int p = 0; p < 2; ++p) {
            int li = p * 512 + t;
            int r = li >> 4, q = li & 15;
            *(uint4*)(lds + r * BSTR + ((q * 16) ^ ((r & 7) << 4))) = pv[p];
        }
        __syncthreads();             // buf0 visible

        float best[8], second[8];
        int   bidx[8];
        #pragma unroll
        for (int s = 0; s < 8; ++s) { best[s] = 3.4e38f; second[s] = 3.4e38f; bidx[s] = 0; }

        for (int ct = 0; ct < NCT; ++ct) {       // ascending code tiles
            char* cur = lds + (ct & 1) * BUFSZ;
            char* nxt = lds + ((ct + 1) & 1) * BUFSZ;
            uint4 pv2[2];
            if (ct < NCT - 1) {                  // issue-early next B tile
                const uint4* bg2 = (const uint4*)Bsp + (size_t)(ct + 1) * 1024;
                #pragma unroll
                for (int p = 0; p < 2; ++p) pv2[p] = bg2[p * 512 + t];
            }

            f32x4 acc[2][2];
            #pragma unroll
            for (int fr = 0; fr < 2; ++fr)
                #pragma unroll
                for (int fc = 0; fc < 2; ++fc)
                    acc[fr][fc] = (f32x4){0.f, 0.f, 0.f, 0.f};

            // term order per acc FP-identical to R6/R7
            #pragma unroll
            for (int fc = 0; fc < 2; ++fc) {
                const char* bp = cur + (cg * 32 + fc * 16 + lan15) * BSTR;
                bf16x8 b0 = *(const bf16x8*)(bp + kofs[0]);
                bf16x8 b1 = *(const bf16x8*)(bp + kofs[1]);
                acc[0][fc] = __builtin_amdgcn_mfma_f32_16x16x32_bf16(a00, b0, acc[0][fc], 0, 0, 0);
                acc[1][fc] = __builtin_amdgcn_mfma_f32_16x16x32_bf16(a10, b0, acc[1][fc], 0, 0, 0);
                acc[0][fc] = __builtin_amdgcn_mfma_f32_16x16x32_bf16(a01, b1, acc[0][fc], 0, 0, 0);
                acc[1][fc] = __builtin_amdgcn_mfma_f32_16x16x32_bf16(a11, b1, acc[1][fc], 0, 0, 0);
                bf16x8 b2 = *(const bf16x8*)(bp + kofs[2]);
                acc[0][fc] = __builtin_amdgcn_mfma_f32_16x16x32_bf16(a00, b2, acc[0][fc], 0, 0, 0);
                acc[1][fc] = __builtin_amdgcn_mfma_f32_16x16x32_bf16(a10, b2, acc[1][fc], 0, 0, 0);
                bf16x8 b3 = *(const bf16x8*)(bp + kofs[3]);
                acc[0][fc] = __builtin_amdgcn_mfma_f32_16x16x32_bf16(a01, b3, acc[0][fc], 0, 0, 0);
                acc[1][fc] = __builtin_amdgcn_mfma_f32_16x16x32_bf16(a11, b3, acc[1][fc], 0, 0, 0);
                acc[0][fc] = __builtin_amdgcn_mfma_f32_16x16x32_bf16(a02, b0, acc[0][fc], 0, 0, 0);
                acc[1][fc] = __builtin_amdgcn_mfma_f32_16x16x32_bf16(a12, b0, acc[1][fc], 0, 0, 0);
                acc[0][fc] = __builtin_amdgcn_mfma_f32_16x16x32_bf16(a03, b1, acc[0][fc], 0, 0, 0);
                acc[1][fc] = __builtin_amdgcn_mfma_f32_16x16x32_bf16(a13, b1, acc[1][fc], 0, 0, 0);
            }

            // write-late staging into the OTHER buffer (no reader conflict)
            if (ct < NCT - 1) {
                #pragma unroll
                for (int p = 0; p < 2; ++p) {
                    int li = p * 512 + t;
                    int r = li >> 4, q = li & 15;
                    *(uint4*)(nxt + r * BSTR + ((q * 16) ^ ((r & 7) << 4))) = pv2[p];
                }
            }

            // epilogue: u = esq/2 - dot; branchless (best, second, idx)
            #pragma unroll
            for (int fc = 0; fc < 2; ++fc) {
                int col = ct * BN + cg * 32 + fc * 16 + lan15;
                float eh = esqh_s[col];
                #pragma unroll
                for (int fr = 0; fr < 2; ++fr) {
                    #pragma unroll
                    for (int r = 0; r < 4; ++r) {
                        float u = eh - acc[fr][fc][r];
                        int s = fr * 4 + r;
                        second[s] = fminf(second[s], fmaxf(u, best[s]));
                        bidx[s] = (u < best[s]) ? col : bidx[s];
                        best[s] = fminf(u, best[s]);
                    }
                }
            }
            __syncthreads();                      // nxt written & cur reads done
        }

        // intra-wave reduce over 16-lane groups (lex: ties -> smaller col)
        #pragma unroll
        for (int s = 0; s < 8; ++s) {
            float b = best[s], sc = second[s];
            int bi = bidx[s];
            #pragma unroll
            for (int off = 1; off <= 8; off <<= 1) {
                float ob = __shfl_xor(b, off);
                float os = __shfl_xor(sc, off);
                int   oi = __shfl_xor(bi, off);
                float mx = fmaxf(b, ob);
                sc = fminf(fminf(sc, os), mx);
                if (ob < b) { b = ob; bi = oi; }
                else if (ob == b) bi = min(bi, oi);
            }
            best[s] = b; second[s] = sc; bidx[s] = bi;
        }
        if (lan15 == 0) {
            #pragma unroll
            for (int s = 0; s < 8; ++s) {
                int row = rg * 32 + (s >> 2) * 16 + (l >> 4) * 4 + (s & 3);
                cb_best[cg][row] = best[s];
                cb_sec[cg][row]  = second[s];
                cb_idx[cg][row]  = bidx[s];
            }
        }
    }
    __syncthreads();
    // cross-wave (col-group) combine; each cg candidate is lex-min of its set
    if (t < BM) {
        float b0 = cb_best[0][t], b1 = cb_best[1][t];
        float s0 = cb_sec[0][t],  s1 = cb_sec[1][t];
        int   i0 = cb_idx[0][t],  i1 = cb_idx[1][t];
        float b; int bi;
        if (b1 < b0 || (b1 == b0 && i1 < i0)) { b = b1; bi = i1; }
        else                                  { b = b0; bi = i0; }
        float sec = fminf(fminf(s0, s1), fmaxf(b0, b1));
        int gid = row0 + t;
        idx_out[gid] = (float)bi;
        if (sec - b <= EPS_U) {
            int slot = atomicAdd(cnt, 1);
            if (slot < NTOK) wl[slot] = gid;
        }
    }
}

// ---------------------- K1b: exact recompute for worklisted (near-tie) tokens
__global__ __launch_bounds__(256) void fallback_kernel(
    const float* __restrict__ z, const float* __restrict__ E,
    const float* __restrict__ esq_g, float* __restrict__ idx_out,
    const int* __restrict__ wl, const int* __restrict__ cnt_p) {
    __shared__ __align__(16) float es[DIM][128];   // 32KB [k][code]
    __shared__ __align__(16) float zl[16][72];     // padded
    __shared__ float zqs[16];

    const int t = threadIdx.x;
    const int tg = t >> 4;           // token slot 0..15
    const int cs = t & 15;           // code slice (8 codes per tile)
    const int cnt = min(*cnt_p, NTOK);

    for (int chunk = blockIdx.x; chunk * 16 < cnt; chunk += 256) {
        const int base = chunk * 16;
        const int nval = min(16, cnt - base);
        const int tok = wl[base + (tg < nval ? tg : 0)];
        {
            float4 v = ((const float4*)z)[(size_t)tok * 16 + cs];
            *(float4*)&zl[tg][cs * 4] = v;
        }
        __syncthreads();
        if (t < 16) {                // zq per slot, sequential k (as R1)
            float s = 0.f;
            for (int k = 0; k < DIM; ++k) { float v = zl[t][k]; s += v * v; }
            zqs[t] = s;
        }
        __syncthreads();
        const float zq = zqs[tg];

        float best = 3.4e38f;
        int bi = 0;
        for (int tile = 0; tile < 8; ++tile) {   // ascending code tiles
            const float4* eg = (const float4*)(E + (size_t)tile * 128 * DIM);
            #pragma unroll
            for (int p = 0; p < 8; ++p) {        // R2 staging pattern verbatim
                int li = p * 256 + t;
                int c = li & 127, k4 = li >> 7;
                float4 v = eg[c * 16 + k4];
                es[k4 * 4 + 0][c] = v.x;
                es[k4 * 4 + 1][c] = v.y;
                es[k4 * 4 + 2][c] = v.z;
                es[k4 * 4 + 3][c] = v.w;
            }
            __syncthreads();

            float acc[8];
            #pragma unroll
            for (int n = 0; n < 8; ++n) acc[n] = 0.f;
            #pragma unroll 8
            for (int k = 0; k < DIM; ++k) {      // sequential fp32 FMA over K
                float a = zl[tg][k];
                float4 b0 = *(const float4*)&es[k][cs * 8 + 0];
                float4 b1 = *(const float4*)&es[k][cs * 8 + 4];
                float b[8] = {b0.x, b0.y, b0.z, b0.w, b1.x, b1.y, b1.z, b1.w};
                #pragma unroll
                for (int n = 0; n < 8; ++n) acc[n] += a * b[n];
            }
            #pragma unroll
            for (int n = 0; n < 8; ++n) {        // ascending code index, strict <
                int c = tile * 128 + cs * 8 + n;
                float d = (zq - 2.0f * acc[n]) + esq_g[c];
                if (d < best) { best = d; bi = c; }
            }
            __syncthreads();
        }
        #pragma unroll
        for (int off = 1; off <= 8; off <<= 1) {
            float ob = __shfl_xor(best, off);
            int   oi = __shfl_xor(bi, off);
            if (ob < best || (ob == best && oi < bi)) { best = ob; bi = oi; }
        }
        if (cs == 0 && tg < nval) idx_out[tok] = (float)bi;
        __syncthreads();
    }
}

// ------------------------------- K2: gather z_q, write out0, loss partials
__global__ __launch_bounds__(256) void gather_kernel(
    const float* __restrict__ z, const float* __restrict__ E,
    const float* __restrict__ idx_f, float* __restrict__ out0,
    float* __restrict__ partials) {
    __shared__ float red[4];
    const int t = threadIdx.x;
    const int token = blockIdx.x * 16 + (t >> 4);
    const int part  = t & 15;

    int id = (int)idx_f[token];
    const float4* z4 = (const float4*)z;
    const float4* E4 = (const float4*)E;
    float4 zv = z4[(size_t)token * 16 + part];
    float4 ev = E4[(size_t)id * 16 + part];

    float dx = ev.x - zv.x, dy = ev.y - zv.y, dz = ev.z - zv.z, dw = ev.w - zv.w;
    float4 o;
    o.x = zv.x + dx; o.y = zv.y + dy; o.z = zv.z + dz; o.w = zv.w + dw;
    ((float4*)out0)[(size_t)token * 16 + part] = o;

    float ls = dx * dx + dy * dy + dz * dz + dw * dw;
    #pragma unroll
    for (int off = 32; off >= 1; off >>= 1) ls += __shfl_xor(ls, off);
    if ((t & 63) == 0) red[t >> 6] = ls;
    __syncthreads();
    if (t == 0) partials[blockIdx.x] = red[0] + red[1] + red[2] + red[3];
}

// ------------------------------------------------------- K3: final loss
__global__ __launch_bounds__(256) void loss_kernel(
    const float* __restrict__ partials, int n, float* __restrict__ loss_out) {
    __shared__ float red[4];
    const int t = threadIdx.x;
    float s = 0.f;
    for (int i = t; i < n; i += 256) s += partials[i];
    #pragma unroll
    for (int off = 32; off >= 1; off >>= 1) s += __shfl_xor(s, off);
    if ((t & 63) == 0) red[t >> 6] = s;
    __syncthreads();
    if (t == 0) {
        float tot = red[0] + red[1] + red[2] + red[3];
        float m = tot / (float)(NTOK * DIM);
        loss_out[0] = m + 0.25f * m;
    }
}

extern "C" void kernel_launch(void* const* d_in, const int* in_sizes, int n_in,
                              void* d_out, int out_size, void* d_ws, size_t ws_size,
                              hipStream_t stream) {
    const float* z = (const float*)d_in[0];       // [131072, 64] f32
    const float* E = (const float*)d_in[1];       // [1024, 64] f32
    float* out = (float*)d_out;

    char* wsb = (char*)d_ws;
    float*          esq      = (float*)(wsb);              // 4 KB
    float*          esqh     = (float*)(wsb + 4096);       // 4 KB
    float*          partials = (float*)(wsb + 8192);       // 32 KB
    int*            cnt      = (int*)(wsb + 40960);        // 4 KB region
    int*            wl       = (int*)(wsb + 45056);        // 512 KB
    unsigned short* Bsp      = (unsigned short*)(wsb + 45056 + 524288); // 256 KB

    prep_kernel<<<256, 256, 0, stream>>>(E, Bsp, esq, esqh, cnt);
    mfma_argmin_kernel<<<NTOK / BM, 512, 0, stream>>>(z, Bsp, esqh,
                                                      out + IDX_OFF, cnt, wl);
    fallback_kernel<<<256, 256, 0, stream>>>(z, E, esq, out + IDX_OFF, wl, cnt);
    gather_kernel<<<NTOK / 16, 256, 0, stream>>>(z, E, out + IDX_OFF, out, partials);
    loss_kernel<<<1, 256, 0, stream>>>(partials, NTOK / 16, out + LOSS_OFF);
}

// Round 9
// 178.268 us; speedup vs baseline: 1.8305x; 1.8305x over previous
//
#include <hip/hip_runtime.h>

#define NTOK   131072
#define KCODES 1024
#define DIM    64
#define BM     128
#define BN     64
#define NCT    (KCODES / BN)         // 16 code tiles

#define LOSS_OFF (NTOK * DIM)        // 8388608
#define IDX_OFF  (LOSS_OFF + 1)      // 8388609

#define EPS_U 6e-5f                  // u-metric gap threshold (d-gap = 2u)

typedef __attribute__((ext_vector_type(8))) short bf16x8;
typedef __attribute__((ext_vector_type(4))) float f32x4;
typedef __attribute__((ext_vector_type(4))) unsigned short ush4;

#if defined(__has_builtin)
#if __has_builtin(__builtin_amdgcn_global_load_lds)
#define HAVE_GLD 1
#endif
#endif

#ifdef HAVE_GLD
typedef const __attribute__((address_space(1))) unsigned int* gas_u32p;
typedef __attribute__((address_space(3))) unsigned int* las_u32p;
#define GLD16(ldst, gsrc) \
    __builtin_amdgcn_global_load_lds((gas_u32p)(gsrc), (las_u32p)(ldst), 16, 0, 0)
#endif

__device__ inline unsigned short bf16rtn(float x) {
    unsigned u = __float_as_uint(x);
    return (unsigned short)((u + 0x7fffu + ((u >> 16) & 1u)) >> 16);
}

// ---- K0: split E -> bf16 hi|lo PRE-SWIZZLED per-tile layout, esq, clear cnt
// Tile ct = codes [ct*64,(ct+1)*64). Global byte of (code c, 16B-chunk q):
// c*256 + ((q*16) ^ ((c&7)<<4)) (+byte-in-chunk). Kernel copies tiles to LDS
// LINEARLY (global_load_lds), reads with the same XOR -> content identical to
// the R7/R8 Bs layout (absmax-0 pedigree).
__global__ __launch_bounds__(256) void prep_kernel(const float* __restrict__ E,
                                                   unsigned short* __restrict__ Bswz,
                                                   float* __restrict__ esq,
                                                   float* __restrict__ esqh,
                                                   int* __restrict__ cnt) {
    const int t = threadIdx.x, b = blockIdx.x;
    if (b == 0 && t == 0) cnt[0] = 0;
    int id = b * 256 + t;                      // 65536 = 1024 x 64
    int c = id >> 6, k = id & 63;
    float x = E[id];
    unsigned short h = bf16rtn(x);
    float hf = __uint_as_float(((unsigned)h) << 16);
    unsigned short lo = bf16rtn(x - hf);
    int rx = (c & 7) << 4;
    int qh = (k >> 3) << 4;                    // 16B chunk byte offset
    int ob = (k & 7) << 1;                     // byte within chunk
    Bswz[(c * 256 + (qh ^ rx) + ob) >> 1]           = h;
    Bswz[(c * 256 + ((128 + qh) ^ rx) + ob) >> 1]   = lo;
    if (b < 4) {                               // esq: arithmetic verbatim (R1-R8)
        int cc = b * 256 + t;
        const float4* row = (const float4*)(E + cc * DIM);
        float s = 0.f;
        #pragma unroll
        for (int i = 0; i < DIM / 4; ++i) {
            float4 v = row[i];
            s += v.x * v.x + v.y * v.y + v.z * v.z + v.w * v.w;
        }
        esq[cc] = s;
        esqh[cc] = 0.5f * s;                   // exact
    }
}

// ------------------------------------------------- K1: MFMA distances + argmin
// 512 thr = 8 waves (4 rg x 2 cg), wave tile 32 tok x 32 codes, 16 tiles of 64.
// K=192 split GEMM, per-acc term order hh,hh,lh,lh,hl,hl. A-hi in regs (16),
// A-lo read from LDS; B staged by global_load_lds from pre-swizzled global
// into double-buffered Bs (Bs0 overlays dead A-hi region). 3 blocks/CU target.
__global__ __launch_bounds__(512, 6) void mfma_argmin_kernel(
    const float* __restrict__ z, const unsigned short* __restrict__ Bswz,
    const float* __restrict__ esqh_g, float* __restrict__ idx_out,
    int* __restrict__ cnt, int* __restrict__ wl) {
    // [0,16K): A-hi then Bs0 | [16K,32K): A-lo (live) | [32K,48K): Bs1
    __shared__ __align__(16) char lds[49152];
    __shared__ __align__(16) char aux[4096];   // esqh_s; cb_* overlay at end
    float* esqh_s  = (float*)aux;
    float* cb_best = (float*)aux;              // [2][128] after loop
    float* cb_sec  = (float*)(aux + 1024);
    int*   cb_idx  = (int*)(aux + 2048);

    const int t = threadIdx.x;
    const int l = t & 63;
    const int w = t >> 6;            // wave 0..7
    const int rg = w >> 1;           // row group (32 tokens)
    const int cg = w & 1;            // col group (32 codes)
    const int lan15 = l & 15;
    const int kp16 = (l >> 4) * 16;  // k-group byte offset within fragment
    const int xr = (lan15 & 7) << 4;
    const int row0 = blockIdx.x * BM;
    const char* gb = (const char*)Bswz;
    const int goff = w * 2048 + l * 16;        // per-thread byte in tile

    // issue tile0 -> Bs1 [32K,48K) immediately (hides under prologue)
#ifdef HAVE_GLD
    GLD16(lds + 32768 + w * 2048,        gb + goff);
    GLD16(lds + 32768 + w * 2048 + 1024, gb + goff + 1024);
#else
    uint4 pv0a = *(const uint4*)(gb + goff);
    uint4 pv0b = *(const uint4*)(gb + goff + 1024);
#endif

    // stage esqh
    esqh_s[t]       = esqh_g[t];
    esqh_s[512 + t] = esqh_g[512 + t];

    // z load + hi/lo split -> A-hi [0,16K) rows*128B, A-lo [16K,32K)
    {
        const float4* zg = (const float4*)(z + (size_t)row0 * DIM);
        float4 av[4];
        #pragma unroll
        for (int p = 0; p < 4; ++p) av[p] = zg[p * 512 + t];
        #pragma unroll
        for (int p = 0; p < 4; ++p) {
            int li = p * 512 + t;
            int r = li >> 4, q = li & 15;
            float xs[4] = {av[p].x, av[p].y, av[p].z, av[p].w};
            ush4 hv, lv;
            #pragma unroll
            for (int j = 0; j < 4; ++j) {
                unsigned short h = bf16rtn(xs[j]);
                float hf = __uint_as_float(((unsigned)h) << 16);
                hv[j] = h;
                lv[j] = bf16rtn(xs[j] - hf);
            }
            int rxw = (r & 7) << 4;
            int o = ((q * 8) ^ rxw);
            *(ush4*)(lds + r * 128 + o)         = hv;
            *(ush4*)(lds + 16384 + r * 128 + o) = lv;
        }
    }
#ifndef HAVE_GLD
    *(uint4*)(lds + 32768 + goff)        = pv0a;
    *(uint4*)(lds + 32768 + goff + 1024) = pv0b;
#endif
    __syncthreads();

    const int ko0 = kp16 ^ xr;                 // k0-31 quarter
    const int ko1 = (64 + kp16) ^ xr;          // k32-63 quarter
    const int arow = (rg * 32 + lan15) * 128;
    const char* alo = lds + 16384 + arow;      // A-lo base (fr1 = +2048)

    // preload A-hi fragments (ct-invariant), then region is dead -> Bs0
    bf16x8 ah00 = *(const bf16x8*)(lds + arow + ko0);
    bf16x8 ah01 = *(const bf16x8*)(lds + arow + ko1);
    bf16x8 ah10 = *(const bf16x8*)(lds + arow + 2048 + ko0);
    bf16x8 ah11 = *(const bf16x8*)(lds + arow + 2048 + ko1);
    __syncthreads();                 // all A-hi reads done; tile0 loads drained

    float best[8], second[8];
    int   bidx[8];
    #pragma unroll
    for (int s = 0; s < 8; ++s) { best[s] = 3.4e38f; second[s] = 3.4e38f; bidx[s] = 0; }

    const int brow = (cg * 32 + lan15) * 256;  // + fc*4096 (imm)

    for (int ct = 0; ct < NCT; ++ct) {         // ascending code tiles
        // cur: ct even -> Bs1 [32K), odd -> Bs0 [0); prefetch into the other
        char* cur = lds + ((ct & 1) ^ 1) * 32768;
        if (ct < NCT - 1) {
            char* nbuf = lds + (ct & 1) * 32768;
            const char* g = gb + (ct + 1) * 16384 + goff;
#ifdef HAVE_GLD
            GLD16(nbuf + w * 2048,        g);
            GLD16(nbuf + w * 2048 + 1024, g + 1024);
#else
            *(uint4*)(nbuf + goff)        = *(const uint4*)(g);
            *(uint4*)(nbuf + goff + 1024) = *(const uint4*)(g + 1024);
#endif
        }

        f32x4 acc[2][2];
        #pragma unroll
        for (int fr = 0; fr < 2; ++fr)
            #pragma unroll
            for (int fc = 0; fc < 2; ++fc)
                acc[fr][fc] = (f32x4){0.f, 0.f, 0.f, 0.f};

        #pragma unroll
        for (int fc = 0; fc < 2; ++fc) {
            const char* bp = cur + brow + fc * 4096;
            bf16x8 b0 = *(const bf16x8*)(bp + ko0);
            bf16x8 b1 = *(const bf16x8*)(bp + ko1);
            // hh
            acc[0][fc] = __builtin_amdgcn_mfma_f32_16x16x32_bf16(ah00, b0, acc[0][fc], 0, 0, 0);
            acc[1][fc] = __builtin_amdgcn_mfma_f32_16x16x32_bf16(ah10, b0, acc[1][fc], 0, 0, 0);
            acc[0][fc] = __builtin_amdgcn_mfma_f32_16x16x32_bf16(ah01, b1, acc[0][fc], 0, 0, 0);
            acc[1][fc] = __builtin_amdgcn_mfma_f32_16x16x32_bf16(ah11, b1, acc[1][fc], 0, 0, 0);
            // lh (A-lo from LDS; b0,b1 die here)
            {
                bf16x8 al0 = *(const bf16x8*)(alo + ko0);
                bf16x8 al1 = *(const bf16x8*)(alo + 2048 + ko0);
                acc[0][fc] = __builtin_amdgcn_mfma_f32_16x16x32_bf16(al0, b0, acc[0][fc], 0, 0, 0);
                acc[1][fc] = __builtin_amdgcn_mfma_f32_16x16x32_bf16(al1, b0, acc[1][fc], 0, 0, 0);
            }
            {
                bf16x8 al2 = *(const bf16x8*)(alo + ko1);
                bf16x8 al3 = *(const bf16x8*)(alo + 2048 + ko1);
                acc[0][fc] = __builtin_amdgcn_mfma_f32_16x16x32_bf16(al2, b1, acc[0][fc], 0, 0, 0);
                acc[1][fc] = __builtin_amdgcn_mfma_f32_16x16x32_bf16(al3, b1, acc[1][fc], 0, 0, 0);
            }
            // hl (B-lo quarters at +128)
            {
                bf16x8 b2 = *(const bf16x8*)(bp + 128 + ko0);
                acc[0][fc] = __builtin_amdgcn_mfma_f32_16x16x32_bf16(ah00, b2, acc[0][fc], 0, 0, 0);
                acc[1][fc] = __builtin_amdgcn_mfma_f32_16x16x32_bf16(ah10, b2, acc[1][fc], 0, 0, 0);
            }
            {
                bf16x8 b3 = *(const bf16x8*)(bp + 128 + ko1);
                acc[0][fc] = __builtin_amdgcn_mfma_f32_16x16x32_bf16(ah01, b3, acc[0][fc], 0, 0, 0);
                acc[1][fc] = __builtin_amdgcn_mfma_f32_16x16x32_bf16(ah11, b3, acc[1][fc], 0, 0, 0);
            }
        }

        // epilogue: u = esq/2 - dot; branchless (best, second, idx)
        #pragma unroll
        for (int fc = 0; fc < 2; ++fc) {
            int col = ct * BN + cg * 32 + fc * 16 + lan15;
            float eh = esqh_s[col];
            #pragma unroll
            for (int fr = 0; fr < 2; ++fr) {
                #pragma unroll
                for (int r = 0; r < 4; ++r) {
                    float u = eh - acc[fr][fc][r];
                    int s = fr * 4 + r;
                    second[s] = fminf(second[s], fmaxf(u, best[s]));
                    bidx[s] = (u < best[s]) ? col : bidx[s];
                    best[s] = fminf(u, best[s]);
                }
            }
        }
        __syncthreads();             // cur reads done; prefetch drained
    }

    // intra-wave reduce over 16-lane groups (lex: ties -> smaller col)
    #pragma unroll
    for (int s = 0; s < 8; ++s) {
        float b = best[s], sc = second[s];
        int bi = bidx[s];
        #pragma unroll
        for (int off = 1; off <= 8; off <<= 1) {
            float ob = __shfl_xor(b, off);
            float os = __shfl_xor(sc, off);
            int   oi = __shfl_xor(bi, off);
            float mx = fmaxf(b, ob);
            sc = fminf(fminf(sc, os), mx);
            if (ob < b) { b = ob; bi = oi; }
            else if (ob == b) bi = min(bi, oi);
        }
        best[s] = b; second[s] = sc; bidx[s] = bi;
    }
    if (lan15 == 0) {                // aux now safe to overlay (post-barrier)
        #pragma unroll
        for (int s = 0; s < 8; ++s) {
            int row = rg * 32 + (s >> 2) * 16 + (l >> 4) * 4 + (s & 3);
            cb_best[cg * BM + row] = best[s];
            cb_sec [cg * BM + row] = second[s];
            cb_idx [cg * BM + row] = bidx[s];
        }
    }
    __syncthreads();
    // cross-wave (col-group) combine; each cg candidate is lex-min of its set
    if (t < BM) {
        float b0 = cb_best[t], b1 = cb_best[BM + t];
        float s0 = cb_sec[t],  s1 = cb_sec[BM + t];
        int   i0 = cb_idx[t],  i1 = cb_idx[BM + t];
        float b; int bi;
        if (b1 < b0 || (b1 == b0 && i1 < i0)) { b = b1; bi = i1; }
        else                                  { b = b0; bi = i0; }
        float sec = fminf(fminf(s0, s1), fmaxf(b0, b1));
        int gid = row0 + t;
        idx_out[gid] = (float)bi;
        if (sec - b <= EPS_U) {
            int slot = atomicAdd(cnt, 1);
            if (slot < NTOK) wl[slot] = gid;
        }
    }
}

// ---------------------- K1b: exact recompute for worklisted (near-tie) tokens
__global__ __launch_bounds__(256) void fallback_kernel(
    const float* __restrict__ z, const float* __restrict__ E,
    const float* __restrict__ esq_g, float* __restrict__ idx_out,
    const int* __restrict__ wl, const int* __restrict__ cnt_p) {
    __shared__ __align__(16) float es[DIM][128];   // 32KB [k][code]
    __shared__ __align__(16) float zl[16][72];     // padded
    __shared__ float zqs[16];

    const int t = threadIdx.x;
    const int tg = t >> 4;           // token slot 0..15
    const int cs = t & 15;           // code slice (8 codes per tile)
    const int cnt = min(*cnt_p, NTOK);

    for (int chunk = blockIdx.x; chunk * 16 < cnt; chunk += 256) {
        const int base = chunk * 16;
        const int nval = min(16, cnt - base);
        const int tok = wl[base + (tg < nval ? tg : 0)];
        {
            float4 v = ((const float4*)z)[(size_t)tok * 16 + cs];
            *(float4*)&zl[tg][cs * 4] = v;
        }
        __syncthreads();
        if (t < 16) {                // zq per slot, sequential k (as R1)
            float s = 0.f;
            for (int k = 0; k < DIM; ++k) { float v = zl[t][k]; s += v * v; }
            zqs[t] = s;
        }
        __syncthreads();
        const float zq = zqs[tg];

        float best = 3.4e38f;
        int bi = 0;
        for (int tile = 0; tile < 8; ++tile) {   // ascending code tiles
            const float4* eg = (const float4*)(E + (size_t)tile * 128 * DIM);
            #pragma unroll
            for (int p = 0; p < 8; ++p) {        // R2 staging pattern verbatim
                int li = p * 256 + t;
                int c = li & 127, k4 = li >> 7;
                float4 v = eg[c * 16 + k4];
                es[k4 * 4 + 0][c] = v.x;
                es[k4 * 4 + 1][c] = v.y;
                es[k4 * 4 + 2][c] = v.z;
                es[k4 * 4 + 3][c] = v.w;
            }
            __syncthreads();

            float acc[8];
            #pragma unroll
            for (int n = 0; n < 8; ++n) acc[n] = 0.f;
            #pragma unroll 8
            for (int k = 0; k < DIM; ++k) {      // sequential fp32 FMA over K
                float a = zl[tg][k];
                float4 b0 = *(const float4*)&es[k][cs * 8 + 0];
                float4 b1 = *(const float4*)&es[k][cs * 8 + 4];
                float b[8] = {b0.x, b0.y, b0.z, b0.w, b1.x, b1.y, b1.z, b1.w};
                #pragma unroll
                for (int n = 0; n < 8; ++n) acc[n] += a * b[n];
            }
            #pragma unroll
            for (int n = 0; n < 8; ++n) {        // ascending code index, strict <
                int c = tile * 128 + cs * 8 + n;
                float d = (zq - 2.0f * acc[n]) + esq_g[c];
                if (d < best) { best = d; bi = c; }
            }
            __syncthreads();
        }
        #pragma unroll
        for (int off = 1; off <= 8; off <<= 1) {
            float ob = __shfl_xor(best, off);
            int   oi = __shfl_xor(bi, off);
            if (ob < best || (ob == best && oi < bi)) { best = ob; bi = oi; }
        }
        if (cs == 0 && tg < nval) idx_out[tok] = (float)bi;
        __syncthreads();
    }
}

// ------------------------------- K2: gather z_q, write out0, loss partials
__global__ __launch_bounds__(256) void gather_kernel(
    const float* __restrict__ z, const float* __restrict__ E,
    const float* __restrict__ idx_f, float* __restrict__ out0,
    float* __restrict__ partials) {
    __shared__ float red[4];
    const int t = threadIdx.x;
    const int token = blockIdx.x * 16 + (t >> 4);
    const int part  = t & 15;

    int id = (int)idx_f[token];
    const float4* z4 = (const float4*)z;
    const float4* E4 = (const float4*)E;
    float4 zv = z4[(size_t)token * 16 + part];
    float4 ev = E4[(size_t)id * 16 + part];

    float dx = ev.x - zv.x, dy = ev.y - zv.y, dz = ev.z - zv.z, dw = ev.w - zv.w;
    float4 o;
    o.x = zv.x + dx; o.y = zv.y + dy; o.z = zv.z + dz; o.w = zv.w + dw;
    ((float4*)out0)[(size_t)token * 16 + part] = o;

    float ls = dx * dx + dy * dy + dz * dz + dw * dw;
    #pragma unroll
    for (int off = 32; off >= 1; off >>= 1) ls += __shfl_xor(ls, off);
    if ((t & 63) == 0) red[t >> 6] = ls;
    __syncthreads();
    if (t == 0) partials[blockIdx.x] = red[0] + red[1] + red[2] + red[3];
}

// ------------------------------------------------------- K3: final loss
__global__ __launch_bounds__(256) void loss_kernel(
    const float* __restrict__ partials, int n, float* __restrict__ loss_out) {
    __shared__ float red[4];
    const int t = threadIdx.x;
    float s = 0.f;
    for (int i = t; i < n; i += 256) s += partials[i];
    #pragma unroll
    for (int off = 32; off >= 1; off >>= 1) s += __shfl_xor(s, off);
    if ((t & 63) == 0) red[t >> 6] = s;
    __syncthreads();
    if (t == 0) {
        float tot = red[0] + red[1] + red[2] + red[3];
        float m = tot / (float)(NTOK * DIM);
        loss_out[0] = m + 0.25f * m;
    }
}

extern "C" void kernel_launch(void* const* d_in, const int* in_sizes, int n_in,
                              void* d_out, int out_size, void* d_ws, size_t ws_size,
                              hipStream_t stream) {
    const float* z = (const float*)d_in[0];       // [131072, 64] f32
    const float* E = (const float*)d_in[1];       // [1024, 64] f32
    float* out = (float*)d_out;

    char* wsb = (char*)d_ws;
    float*          esq      = (float*)(wsb);              // 4 KB
    float*          esqh     = (float*)(wsb + 4096);       // 4 KB
    float*          partials = (float*)(wsb + 8192);       // 32 KB
    int*            cnt      = (int*)(wsb + 40960);        // 4 KB region
    int*            wl       = (int*)(wsb + 45056);        // 512 KB
    unsigned short* Bswz     = (unsigned short*)(wsb + 45056 + 524288); // 256 KB

    prep_kernel<<<256, 256, 0, stream>>>(E, Bswz, esq, esqh, cnt);
    mfma_argmin_kernel<<<NTOK / BM, 512, 0, stream>>>(z, Bswz, esqh,
                                                      out + IDX_OFF, cnt, wl);
    fallback_kernel<<<256, 256, 0, stream>>>(z, E, esq, out + IDX_OFF, wl, cnt);
    gather_kernel<<<NTOK / 16, 256, 0, stream>>>(z, E, out + IDX_OFF, out, partials);
    loss_kernel<<<1, 256, 0, stream>>>(partials, NTOK / 16, out + LOSS_OFF);
}

// Round 10
// 154.465 us; speedup vs baseline: 2.1125x; 1.1541x over previous
//
#include <hip/hip_runtime.h>

#define NTOK   131072
#define KCODES 1024
#define DIM    64
#define BM     128
#define BN     64
#define NCT    (KCODES / BN)         // 16 code tiles

#define LOSS_OFF (NTOK * DIM)        // 8388608
#define IDX_OFF  (LOSS_OFF + 1)      // 8388609

#define EPS_U 6e-5f                  // u-metric gap threshold (d-gap = 2u)

typedef __attribute__((ext_vector_type(8))) short bf16x8;
typedef __attribute__((ext_vector_type(4))) float f32x4;
typedef __attribute__((ext_vector_type(4))) unsigned short ush4;

#if defined(__has_builtin)
#if __has_builtin(__builtin_amdgcn_global_load_lds)
#define HAVE_GLD 1
#endif
#endif

#ifdef HAVE_GLD
typedef const __attribute__((address_space(1))) unsigned int* gas_u32p;
typedef __attribute__((address_space(3))) unsigned int* las_u32p;
#define GLD16(ldst, gsrc) \
    __builtin_amdgcn_global_load_lds((gas_u32p)(gsrc), (las_u32p)(ldst), 16, 0, 0)
#endif

__device__ inline unsigned short bf16rtn(float x) {
    unsigned u = __float_as_uint(x);
    return (unsigned short)((u + 0x7fffu + ((u >> 16) & 1u)) >> 16);
}

// ---- K0: split E -> bf16 hi|lo PRE-SWIZZLED per-tile layout, esq, clear cnt
// Global byte of (code c, 16B-chunk q): c*256 + ((q*16) ^ ((c&7)<<4)).
// Kernel copies tiles to LDS LINEARLY (global_load_lds), reads with the same
// XOR -> content identical to the R7/R8 Bs layout (absmax-0 pedigree).
__global__ __launch_bounds__(256) void prep_kernel(const float* __restrict__ E,
                                                   unsigned short* __restrict__ Bswz,
                                                   float* __restrict__ esq,
                                                   float* __restrict__ esqh,
                                                   int* __restrict__ cnt) {
    const int t = threadIdx.x, b = blockIdx.x;
    if (b == 0 && t == 0) cnt[0] = 0;
    int id = b * 256 + t;                      // 65536 = 1024 x 64
    int c = id >> 6, k = id & 63;
    float x = E[id];
    unsigned short h = bf16rtn(x);
    float hf = __uint_as_float(((unsigned)h) << 16);
    unsigned short lo = bf16rtn(x - hf);
    int rx = (c & 7) << 4;
    int qh = (k >> 3) << 4;                    // 16B chunk byte offset
    int ob = (k & 7) << 1;                     // byte within chunk
    Bswz[(c * 256 + (qh ^ rx) + ob) >> 1]           = h;
    Bswz[(c * 256 + ((128 + qh) ^ rx) + ob) >> 1]   = lo;
    if (b < 4) {                               // esq: arithmetic verbatim (R1-R9)
        int cc = b * 256 + t;
        const float4* row = (const float4*)(E + cc * DIM);
        float s = 0.f;
        #pragma unroll
        for (int i = 0; i < DIM / 4; ++i) {
            float4 v = row[i];
            s += v.x * v.x + v.y * v.y + v.z * v.z + v.w * v.w;
        }
        esq[cc] = s;
        esqh[cc] = 0.5f * s;                   // exact
    }
}

// ------------------------------------------------- K1: MFMA distances + argmin
// 512 thr = 8 waves (4 rg x 2 cg), wave tile 32 tok x 32 codes, 16 tiles of 64.
// K=192 split GEMM, per-acc term order hh,hh,lh,lh,hl,hl. A-hi in regs (16),
// A-lo read from LDS; B staged by global_load_lds from pre-swizzled global
// into double-buffered Bs (Bs0 overlays dead A-hi region).
// launch_bounds (512,4): R8/R9 showed (512,6) forces a pathological 40-VGPR
// + scratch-spill allocation; (512,4) lets the ~80-reg need fit honestly.
__global__ __launch_bounds__(512, 4) void mfma_argmin_kernel(
    const float* __restrict__ z, const unsigned short* __restrict__ Bswz,
    const float* __restrict__ esqh_g, float* __restrict__ idx_out,
    int* __restrict__ cnt, int* __restrict__ wl) {
    // [0,16K): A-hi then Bs0 | [16K,32K): A-lo (live) | [32K,48K): Bs1
    __shared__ __align__(16) char lds[49152];
    __shared__ __align__(16) char aux[4096];   // esqh_s; cb_* overlay at end
    float* esqh_s  = (float*)aux;
    float* cb_best = (float*)aux;              // [2][128] after loop
    float* cb_sec  = (float*)(aux + 1024);
    int*   cb_idx  = (int*)(aux + 2048);

    const int t = threadIdx.x;
    const int l = t & 63;
    const int w = t >> 6;            // wave 0..7
    const int rg = w >> 1;           // row group (32 tokens)
    const int cg = w & 1;            // col group (32 codes)
    const int lan15 = l & 15;
    const int kp16 = (l >> 4) * 16;  // k-group byte offset within fragment
    const int xr = (lan15 & 7) << 4;
    const int row0 = blockIdx.x * BM;
    const char* gb = (const char*)Bswz;
    const int goff = w * 2048 + l * 16;        // per-thread byte in tile

    // issue tile0 -> Bs1 [32K,48K) immediately (hides under prologue)
#ifdef HAVE_GLD
    GLD16(lds + 32768 + w * 2048,        gb + goff);
    GLD16(lds + 32768 + w * 2048 + 1024, gb + goff + 1024);
#else
    uint4 pv0a = *(const uint4*)(gb + goff);
    uint4 pv0b = *(const uint4*)(gb + goff + 1024);
#endif

    // stage esqh
    esqh_s[t]       = esqh_g[t];
    esqh_s[512 + t] = esqh_g[512 + t];

    // z load + hi/lo split -> A-hi [0,16K) rows*128B, A-lo [16K,32K)
    {
        const float4* zg = (const float4*)(z + (size_t)row0 * DIM);
        float4 av[4];
        #pragma unroll
        for (int p = 0; p < 4; ++p) av[p] = zg[p * 512 + t];
        #pragma unroll
        for (int p = 0; p < 4; ++p) {
            int li = p * 512 + t;
            int r = li >> 4, q = li & 15;
            float xs[4] = {av[p].x, av[p].y, av[p].z, av[p].w};
            ush4 hv, lv;
            #pragma unroll
            for (int j = 0; j < 4; ++j) {
                unsigned short h = bf16rtn(xs[j]);
                float hf = __uint_as_float(((unsigned)h) << 16);
                hv[j] = h;
                lv[j] = bf16rtn(xs[j] - hf);
            }
            int rxw = (r & 7) << 4;
            int o = ((q * 8) ^ rxw);
            *(ush4*)(lds + r * 128 + o)         = hv;
            *(ush4*)(lds + 16384 + r * 128 + o) = lv;
        }
    }
#ifndef HAVE_GLD
    *(uint4*)(lds + 32768 + goff)        = pv0a;
    *(uint4*)(lds + 32768 + goff + 1024) = pv0b;
#endif
    __syncthreads();

    const int ko0 = kp16 ^ xr;                 // k0-31 quarter
    const int ko1 = (64 + kp16) ^ xr;          // k32-63 quarter
    const int arow = (rg * 32 + lan15) * 128;
    const char* alo = lds + 16384 + arow;      // A-lo base (fr1 = +2048)

    // preload A-hi fragments (ct-invariant), then region is dead -> Bs0
    bf16x8 ah00 = *(const bf16x8*)(lds + arow + ko0);
    bf16x8 ah01 = *(const bf16x8*)(lds + arow + ko1);
    bf16x8 ah10 = *(const bf16x8*)(lds + arow + 2048 + ko0);
    bf16x8 ah11 = *(const bf16x8*)(lds + arow + 2048 + ko1);
    __syncthreads();                 // all A-hi reads done; tile0 loads drained

    float best[8], second[8];
    int   bidx[8];
    #pragma unroll
    for (int s = 0; s < 8; ++s) { best[s] = 3.4e38f; second[s] = 3.4e38f; bidx[s] = 0; }

    const int brow = (cg * 32 + lan15) * 256;  // + fc*4096 (imm)

    for (int ct = 0; ct < NCT; ++ct) {         // ascending code tiles
        // cur: ct even -> Bs1 [32K), odd -> Bs0 [0); prefetch into the other
        char* cur = lds + ((ct & 1) ^ 1) * 32768;
        if (ct < NCT - 1) {
            char* nbuf = lds + (ct & 1) * 32768;
            const char* g = gb + (ct + 1) * 16384 + goff;
#ifdef HAVE_GLD
            GLD16(nbuf + w * 2048,        g);
            GLD16(nbuf + w * 2048 + 1024, g + 1024);
#else
            *(uint4*)(nbuf + goff)        = *(const uint4*)(g);
            *(uint4*)(nbuf + goff + 1024) = *(const uint4*)(g + 1024);
#endif
        }

        f32x4 acc[2][2];
        #pragma unroll
        for (int fr = 0; fr < 2; ++fr)
            #pragma unroll
            for (int fc = 0; fc < 2; ++fc)
                acc[fr][fc] = (f32x4){0.f, 0.f, 0.f, 0.f};

        #pragma unroll
        for (int fc = 0; fc < 2; ++fc) {
            const char* bp = cur + brow + fc * 4096;
            bf16x8 b0 = *(const bf16x8*)(bp + ko0);
            bf16x8 b1 = *(const bf16x8*)(bp + ko1);
            // hh
            acc[0][fc] = __builtin_amdgcn_mfma_f32_16x16x32_bf16(ah00, b0, acc[0][fc], 0, 0, 0);
            acc[1][fc] = __builtin_amdgcn_mfma_f32_16x16x32_bf16(ah10, b0, acc[1][fc], 0, 0, 0);
            acc[0][fc] = __builtin_amdgcn_mfma_f32_16x16x32_bf16(ah01, b1, acc[0][fc], 0, 0, 0);
            acc[1][fc] = __builtin_amdgcn_mfma_f32_16x16x32_bf16(ah11, b1, acc[1][fc], 0, 0, 0);
            // lh (A-lo from LDS; b0,b1 die after this)
            {
                bf16x8 al0 = *(const bf16x8*)(alo + ko0);
                bf16x8 al1 = *(const bf16x8*)(alo + 2048 + ko0);
                acc[0][fc] = __builtin_amdgcn_mfma_f32_16x16x32_bf16(al0, b0, acc[0][fc], 0, 0, 0);
                acc[1][fc] = __builtin_amdgcn_mfma_f32_16x16x32_bf16(al1, b0, acc[1][fc], 0, 0, 0);
            }
            {
                bf16x8 al2 = *(const bf16x8*)(alo + ko1);
                bf16x8 al3 = *(const bf16x8*)(alo + 2048 + ko1);
                acc[0][fc] = __builtin_amdgcn_mfma_f32_16x16x32_bf16(al2, b1, acc[0][fc], 0, 0, 0);
                acc[1][fc] = __builtin_amdgcn_mfma_f32_16x16x32_bf16(al3, b1, acc[1][fc], 0, 0, 0);
            }
            // hl (B-lo quarters at +128)
            {
                bf16x8 b2 = *(const bf16x8*)(bp + 128 + ko0);
                acc[0][fc] = __builtin_amdgcn_mfma_f32_16x16x32_bf16(ah00, b2, acc[0][fc], 0, 0, 0);
                acc[1][fc] = __builtin_amdgcn_mfma_f32_16x16x32_bf16(ah10, b2, acc[1][fc], 0, 0, 0);
            }
            {
                bf16x8 b3 = *(const bf16x8*)(bp + 128 + ko1);
                acc[0][fc] = __builtin_amdgcn_mfma_f32_16x16x32_bf16(ah01, b3, acc[0][fc], 0, 0, 0);
                acc[1][fc] = __builtin_amdgcn_mfma_f32_16x16x32_bf16(ah11, b3, acc[1][fc], 0, 0, 0);
            }
        }

        // epilogue: u = esq/2 - dot; branchless (best, second, idx)
        #pragma unroll
        for (int fc = 0; fc < 2; ++fc) {
            int col = ct * BN + cg * 32 + fc * 16 + lan15;
            float eh = esqh_s[col];
            #pragma unroll
            for (int fr = 0; fr < 2; ++fr) {
                #pragma unroll
                for (int r = 0; r < 4; ++r) {
                    float u = eh - acc[fr][fc][r];
                    int s = fr * 4 + r;
                    second[s] = fminf(second[s], fmaxf(u, best[s]));
                    bidx[s] = (u < best[s]) ? col : bidx[s];
                    best[s] = fminf(u, best[s]);
                }
            }
        }
        __syncthreads();             // cur reads done; prefetch drained
    }

    // intra-wave reduce over 16-lane groups (lex: ties -> smaller col)
    #pragma unroll
    for (int s = 0; s < 8; ++s) {
        float b = best[s], sc = second[s];
        int bi = bidx[s];
        #pragma unroll
        for (int off = 1; off <= 8; off <<= 1) {
            float ob = __shfl_xor(b, off);
            float os = __shfl_xor(sc, off);
            int   oi = __shfl_xor(bi, off);
            float mx = fmaxf(b, ob);
            sc = fminf(fminf(sc, os), mx);
            if (ob < b) { b = ob; bi = oi; }
            else if (ob == b) bi = min(bi, oi);
        }
        best[s] = b; second[s] = sc; bidx[s] = bi;
    }
    if (lan15 == 0) {                // aux now safe to overlay (post-barrier)
        #pragma unroll
        for (int s = 0; s < 8; ++s) {
            int row = rg * 32 + (s >> 2) * 16 + (l >> 4) * 4 + (s & 3);
            cb_best[cg * BM + row] = best[s];
            cb_sec [cg * BM + row] = second[s];
            cb_idx [cg * BM + row] = bidx[s];
        }
    }
    __syncthreads();
    // cross-wave (col-group) combine; each cg candidate is lex-min of its set
    if (t < BM) {
        float b0 = cb_best[t], b1 = cb_best[BM + t];
        float s0 = cb_sec[t],  s1 = cb_sec[BM + t];
        int   i0 = cb_idx[t],  i1 = cb_idx[BM + t];
        float b; int bi;
        if (b1 < b0 || (b1 == b0 && i1 < i0)) { b = b1; bi = i1; }
        else                                  { b = b0; bi = i0; }
        float sec = fminf(fminf(s0, s1), fmaxf(b0, b1));
        int gid = row0 + t;
        idx_out[gid] = (float)bi;
        if (sec - b <= EPS_U) {
            int slot = atomicAdd(cnt, 1);
            if (slot < NTOK) wl[slot] = gid;
        }
    }
}

// ---------------------- K1b: exact recompute for worklisted (near-tie) tokens
__global__ __launch_bounds__(256) void fallback_kernel(
    const float* __restrict__ z, const float* __restrict__ E,
    const float* __restrict__ esq_g, float* __restrict__ idx_out,
    const int* __restrict__ wl, const int* __restrict__ cnt_p) {
    __shared__ __align__(16) float es[DIM][128];   // 32KB [k][code]
    __shared__ __align__(16) float zl[16][72];     // padded
    __shared__ float zqs[16];

    const int t = threadIdx.x;
    const int tg = t >> 4;           // token slot 0..15
    const int cs = t & 15;           // code slice (8 codes per tile)
    const int cnt = min(*cnt_p, NTOK);

    for (int chunk = blockIdx.x; chunk * 16 < cnt; chunk += 256) {
        const int base = chunk * 16;
        const int nval = min(16, cnt - base);
        const int tok = wl[base + (tg < nval ? tg : 0)];
        {
            float4 v = ((const float4*)z)[(size_t)tok * 16 + cs];
            *(float4*)&zl[tg][cs * 4] = v;
        }
        __syncthreads();
        if (t < 16) {                // zq per slot, sequential k (as R1)
            float s = 0.f;
            for (int k = 0; k < DIM; ++k) { float v = zl[t][k]; s += v * v; }
            zqs[t] = s;
        }
        __syncthreads();
        const float zq = zqs[tg];

        float best = 3.4e38f;
        int bi = 0;
        for (int tile = 0; tile < 8; ++tile) {   // ascending code tiles
            const float4* eg = (const float4*)(E + (size_t)tile * 128 * DIM);
            #pragma unroll
            for (int p = 0; p < 8; ++p) {        // R2 staging pattern verbatim
                int li = p * 256 + t;
                int c = li & 127, k4 = li >> 7;
                float4 v = eg[c * 16 + k4];
                es[k4 * 4 + 0][c] = v.x;
                es[k4 * 4 + 1][c] = v.y;
                es[k4 * 4 + 2][c] = v.z;
                es[k4 * 4 + 3][c] = v.w;
            }
            __syncthreads();

            float acc[8];
            #pragma unroll
            for (int n = 0; n < 8; ++n) acc[n] = 0.f;
            #pragma unroll 8
            for (int k = 0; k < DIM; ++k) {      // sequential fp32 FMA over K
                float a = zl[tg][k];
                float4 b0 = *(const float4*)&es[k][cs * 8 + 0];
                float4 b1 = *(const float4*)&es[k][cs * 8 + 4];
                float b[8] = {b0.x, b0.y, b0.z, b0.w, b1.x, b1.y, b1.z, b1.w};
                #pragma unroll
                for (int n = 0; n < 8; ++n) acc[n] += a * b[n];
            }
            #pragma unroll
            for (int n = 0; n < 8; ++n) {        // ascending code index, strict <
                int c = tile * 128 + cs * 8 + n;
                float d = (zq - 2.0f * acc[n]) + esq_g[c];
                if (d < best) { best = d; bi = c; }
            }
            __syncthreads();
        }
        #pragma unroll
        for (int off = 1; off <= 8; off <<= 1) {
            float ob = __shfl_xor(best, off);
            int   oi = __shfl_xor(bi, off);
            if (ob < best || (ob == best && oi < bi)) { best = ob; bi = oi; }
        }
        if (cs == 0 && tg < nval) idx_out[tok] = (float)bi;
        __syncthreads();
    }
}

// ------------------------------- K2: gather z_q, write out0, loss partials
__global__ __launch_bounds__(256) void gather_kernel(
    const float* __restrict__ z, const float* __restrict__ E,
    const float* __restrict__ idx_f, float* __restrict__ out0,
    float* __restrict__ partials) {
    __shared__ float red[4];
    const int t = threadIdx.x;
    const int token = blockIdx.x * 16 + (t >> 4);
    const int part  = t & 15;

    int id = (int)idx_f[token];
    const float4* z4 = (const float4*)z;
    const float4* E4 = (const float4*)E;
    float4 zv = z4[(size_t)token * 16 + part];
    float4 ev = E4[(size_t)id * 16 + part];

    float dx = ev.x - zv.x, dy = ev.y - zv.y, dz = ev.z - zv.z, dw = ev.w - zv.w;
    float4 o;
    o.x = zv.x + dx; o.y = zv.y + dy; o.z = zv.z + dz; o.w = zv.w + dw;
    ((float4*)out0)[(size_t)token * 16 + part] = o;

    float ls = dx * dx + dy * dy + dz * dz + dw * dw;
    #pragma unroll
    for (int off = 32; off >= 1; off >>= 1) ls += __shfl_xor(ls, off);
    if ((t & 63) == 0) red[t >> 6] = ls;
    __syncthreads();
    if (t == 0) partials[blockIdx.x] = red[0] + red[1] + red[2] + red[3];
}

// ------------------------------------------------------- K3: final loss
__global__ __launch_bounds__(256) void loss_kernel(
    const float* __restrict__ partials, int n, float* __restrict__ loss_out) {
    __shared__ float red[4];
    const int t = threadIdx.x;
    float s = 0.f;
    for (int i = t; i < n; i += 256) s += partials[i];
    #pragma unroll
    for (int off = 32; off >= 1; off >>= 1) s += __shfl_xor(s, off);
    if ((t & 63) == 0) red[t >> 6] = s;
    __syncthreads();
    if (t == 0) {
        float tot = red[0] + red[1] + red[2] + red[3];
        float m = tot / (float)(NTOK * DIM);
        loss_out[0] = m + 0.25f * m;
    }
}

extern "C" void kernel_launch(void* const* d_in, const int* in_sizes, int n_in,
                              void* d_out, int out_size, void* d_ws, size_t ws_size,
                              hipStream_t stream) {
    const float* z = (const float*)d_in[0];       // [131072, 64] f32
    const float* E = (const float*)d_in[1];       // [1024, 64] f32
    float* out = (float*)d_out;

    char* wsb = (char*)d_ws;
    float*          esq      = (float*)(wsb);              // 4 KB
    float*          esqh     = (float*)(wsb + 4096);       // 4 KB
    float*          partials = (float*)(wsb + 8192);       // 32 KB
    int*            cnt      = (int*)(wsb + 40960);        // 4 KB region
    int*            wl       = (int*)(wsb + 45056);        // 512 KB
    unsigned short* Bswz     = (unsigned short*)(wsb + 45056 + 524288); // 256 KB

    prep_kernel<<<256, 256, 0, stream>>>(E, Bswz, esq, esqh, cnt);
    mfma_argmin_kernel<<<NTOK / BM, 512, 0, stream>>>(z, Bswz, esqh,
                                                      out + IDX_OFF, cnt, wl);
    fallback_kernel<<<256, 256, 0, stream>>>(z, E, esq, out + IDX_OFF, wl, cnt);
    gather_kernel<<<NTOK / 16, 256, 0, stream>>>(z, E, out + IDX_OFF, out, partials);
    loss_kernel<<<1, 256, 0, stream>>>(partials, NTOK / 16, out + LOSS_OFF);
}

// Round 11
// 151.744 us; speedup vs baseline: 2.1504x; 1.0179x over previous
//
#include <hip/hip_runtime.h>

#define NTOK   131072
#define KCODES 1024
#define DIM    64
#define BM     128
#define BN     64
#define NCT    (KCODES / BN)         // 16 code tiles

#define LOSS_OFF (NTOK * DIM)        // 8388608
#define IDX_OFF  (LOSS_OFF + 1)      // 8388609

#define EPS_U 6e-5f                  // u-metric gap threshold (d-gap = 2u)

typedef __attribute__((ext_vector_type(8))) short bf16x8;
typedef __attribute__((ext_vector_type(4))) float f32x4;
typedef __attribute__((ext_vector_type(4))) unsigned short ush4;

#if defined(__has_builtin)
#if __has_builtin(__builtin_amdgcn_global_load_lds)
#define HAVE_GLD 1
#endif
#endif

#ifdef HAVE_GLD
typedef const __attribute__((address_space(1))) unsigned int* gas_u32p;
typedef __attribute__((address_space(3))) unsigned int* las_u32p;
#define GLD16(ldst, gsrc) \
    __builtin_amdgcn_global_load_lds((gas_u32p)(gsrc), (las_u32p)(ldst), 16, 0, 0)
#endif

__device__ inline unsigned short bf16rtn(float x) {
    unsigned u = __float_as_uint(x);
    return (unsigned short)((u + 0x7fffu + ((u >> 16) & 1u)) >> 16);
}

// ---- K0: split E -> bf16 hi|lo PRE-SWIZZLED per-tile layout, esq, clear cnt
__global__ __launch_bounds__(256) void prep_kernel(const float* __restrict__ E,
                                                   unsigned short* __restrict__ Bswz,
                                                   float* __restrict__ esqh,
                                                   float* __restrict__ esq,
                                                   int* __restrict__ cnt) {
    const int t = threadIdx.x, b = blockIdx.x;
    if (b == 0 && t == 0) cnt[0] = 0;
    int id = b * 256 + t;                      // 65536 = 1024 x 64
    int c = id >> 6, k = id & 63;
    float x = E[id];
    unsigned short h = bf16rtn(x);
    float hf = __uint_as_float(((unsigned)h) << 16);
    unsigned short lo = bf16rtn(x - hf);
    int rx = (c & 7) << 4;
    int qh = (k >> 3) << 4;                    // 16B chunk byte offset
    int ob = (k & 7) << 1;                     // byte within chunk
    Bswz[(c * 256 + (qh ^ rx) + ob) >> 1]           = h;
    Bswz[(c * 256 + ((128 + qh) ^ rx) + ob) >> 1]   = lo;
    if (b < 4) {                               // esq: arithmetic verbatim (R1-R10)
        int cc = b * 256 + t;
        const float4* row = (const float4*)(E + cc * DIM);
        float s = 0.f;
        #pragma unroll
        for (int i = 0; i < DIM / 4; ++i) {
            float4 v = row[i];
            s += v.x * v.x + v.y * v.y + v.z * v.z + v.w * v.w;
        }
        esq[cc] = s;
        esqh[cc] = 0.5f * s;                   // exact
    }
}

// ------------------------------------------------- K1: MFMA distances + argmin
// As R10 (512 thr, A-hi regs / A-lo LDS, dbuf Bs via global_load_lds, (512,4))
// + fused epilogue: writes z_q_st rows (candidate idx), per-block loss partial
// (flagged excluded), flag bitmap (ballot full-word), compacted worklist.
__global__ __launch_bounds__(512, 4) void mfma_argmin_kernel(
    const float* __restrict__ z, const float* __restrict__ E,
    const unsigned short* __restrict__ Bswz, const float* __restrict__ esqh_g,
    float* __restrict__ idx_out, float* __restrict__ out0,
    float* __restrict__ partials, int* __restrict__ cnt, int* __restrict__ wl,
    unsigned long long* __restrict__ bitmap) {
    // [0,16K): A-hi then Bs0 | [16K,32K): A-lo (live) | [32K,48K): Bs1
    __shared__ __align__(16) char lds[49152];
    __shared__ __align__(16) char aux[4096];
    float* esqh_s  = (float*)aux;              // dead after main loop
    float* cb_best = (float*)aux;              // [2][128]
    float* cb_sec  = (float*)(aux + 1024);
    int*   cb_idx  = (int*)(aux + 2048);
    int*   fbi     = (int*)(aux + 3072);       // [128] packed idx|flag
    float* wred    = (float*)(aux + 3584);     // [8]

    const int t = threadIdx.x;
    const int l = t & 63;
    const int w = t >> 6;            // wave 0..7
    const int rg = w >> 1;           // row group (32 tokens)
    const int cg = w & 1;            // col group (32 codes)
    const int lan15 = l & 15;
    const int kp16 = (l >> 4) * 16;
    const int xr = (lan15 & 7) << 4;
    const int row0 = blockIdx.x * BM;
    const char* gb = (const char*)Bswz;
    const int goff = w * 2048 + l * 16;

    // issue tile0 -> Bs1 immediately (hides under prologue)
#ifdef HAVE_GLD
    GLD16(lds + 32768 + w * 2048,        gb + goff);
    GLD16(lds + 32768 + w * 2048 + 1024, gb + goff + 1024);
#else
    uint4 pv0a = *(const uint4*)(gb + goff);
    uint4 pv0b = *(const uint4*)(gb + goff + 1024);
#endif

    esqh_s[t]       = esqh_g[t];
    esqh_s[512 + t] = esqh_g[512 + t];

    // z load + hi/lo split -> A-hi [0,16K), A-lo [16K,32K)
    {
        const float4* zg = (const float4*)(z + (size_t)row0 * DIM);
        float4 av[4];
        #pragma unroll
        for (int p = 0; p < 4; ++p) av[p] = zg[p * 512 + t];
        #pragma unroll
        for (int p = 0; p < 4; ++p) {
            int li = p * 512 + t;
            int r = li >> 4, q = li & 15;
            float xs[4] = {av[p].x, av[p].y, av[p].z, av[p].w};
            ush4 hv, lv;
            #pragma unroll
            for (int j = 0; j < 4; ++j) {
                unsigned short h = bf16rtn(xs[j]);
                float hf = __uint_as_float(((unsigned)h) << 16);
                hv[j] = h;
                lv[j] = bf16rtn(xs[j] - hf);
            }
            int rxw = (r & 7) << 4;
            int o = ((q * 8) ^ rxw);
            *(ush4*)(lds + r * 128 + o)         = hv;
            *(ush4*)(lds + 16384 + r * 128 + o) = lv;
        }
    }
#ifndef HAVE_GLD
    *(uint4*)(lds + 32768 + goff)        = pv0a;
    *(uint4*)(lds + 32768 + goff + 1024) = pv0b;
#endif
    __syncthreads();

    const int ko0 = kp16 ^ xr;
    const int ko1 = (64 + kp16) ^ xr;
    const int arow = (rg * 32 + lan15) * 128;
    const char* alo = lds + 16384 + arow;

    bf16x8 ah00 = *(const bf16x8*)(lds + arow + ko0);
    bf16x8 ah01 = *(const bf16x8*)(lds + arow + ko1);
    bf16x8 ah10 = *(const bf16x8*)(lds + arow + 2048 + ko0);
    bf16x8 ah11 = *(const bf16x8*)(lds + arow + 2048 + ko1);
    __syncthreads();                 // A-hi reads done; tile0 drained

    float best[8], second[8];
    int   bidx[8];
    #pragma unroll
    for (int s = 0; s < 8; ++s) { best[s] = 3.4e38f; second[s] = 3.4e38f; bidx[s] = 0; }

    const int brow = (cg * 32 + lan15) * 256;

    for (int ct = 0; ct < NCT; ++ct) {
        char* cur = lds + ((ct & 1) ^ 1) * 32768;
        if (ct < NCT - 1) {
            char* nbuf = lds + (ct & 1) * 32768;
            const char* g = gb + (ct + 1) * 16384 + goff;
#ifdef HAVE_GLD
            GLD16(nbuf + w * 2048,        g);
            GLD16(nbuf + w * 2048 + 1024, g + 1024);
#else
            *(uint4*)(nbuf + goff)        = *(const uint4*)(g);
            *(uint4*)(nbuf + goff + 1024) = *(const uint4*)(g + 1024);
#endif
        }

        f32x4 acc[2][2];
        #pragma unroll
        for (int fr = 0; fr < 2; ++fr)
            #pragma unroll
            for (int fc = 0; fc < 2; ++fc)
                acc[fr][fc] = (f32x4){0.f, 0.f, 0.f, 0.f};

        #pragma unroll
        for (int fc = 0; fc < 2; ++fc) {
            const char* bp = cur + brow + fc * 4096;
            bf16x8 b0 = *(const bf16x8*)(bp + ko0);
            bf16x8 b1 = *(const bf16x8*)(bp + ko1);
            acc[0][fc] = __builtin_amdgcn_mfma_f32_16x16x32_bf16(ah00, b0, acc[0][fc], 0, 0, 0);
            acc[1][fc] = __builtin_amdgcn_mfma_f32_16x16x32_bf16(ah10, b0, acc[1][fc], 0, 0, 0);
            acc[0][fc] = __builtin_amdgcn_mfma_f32_16x16x32_bf16(ah01, b1, acc[0][fc], 0, 0, 0);
            acc[1][fc] = __builtin_amdgcn_mfma_f32_16x16x32_bf16(ah11, b1, acc[1][fc], 0, 0, 0);
            {
                bf16x8 al0 = *(const bf16x8*)(alo + ko0);
                bf16x8 al1 = *(const bf16x8*)(alo + 2048 + ko0);
                acc[0][fc] = __builtin_amdgcn_mfma_f32_16x16x32_bf16(al0, b0, acc[0][fc], 0, 0, 0);
                acc[1][fc] = __builtin_amdgcn_mfma_f32_16x16x32_bf16(al1, b0, acc[1][fc], 0, 0, 0);
            }
            {
                bf16x8 al2 = *(const bf16x8*)(alo + ko1);
                bf16x8 al3 = *(const bf16x8*)(alo + 2048 + ko1);
                acc[0][fc] = __builtin_amdgcn_mfma_f32_16x16x32_bf16(al2, b1, acc[0][fc], 0, 0, 0);
                acc[1][fc] = __builtin_amdgcn_mfma_f32_16x16x32_bf16(al3, b1, acc[1][fc], 0, 0, 0);
            }
            {
                bf16x8 b2 = *(const bf16x8*)(bp + 128 + ko0);
                acc[0][fc] = __builtin_amdgcn_mfma_f32_16x16x32_bf16(ah00, b2, acc[0][fc], 0, 0, 0);
                acc[1][fc] = __builtin_amdgcn_mfma_f32_16x16x32_bf16(ah10, b2, acc[1][fc], 0, 0, 0);
            }
            {
                bf16x8 b3 = *(const bf16x8*)(bp + 128 + ko1);
                acc[0][fc] = __builtin_amdgcn_mfma_f32_16x16x32_bf16(ah01, b3, acc[0][fc], 0, 0, 0);
                acc[1][fc] = __builtin_amdgcn_mfma_f32_16x16x32_bf16(ah11, b3, acc[1][fc], 0, 0, 0);
            }
        }

        #pragma unroll
        for (int fc = 0; fc < 2; ++fc) {
            int col = ct * BN + cg * 32 + fc * 16 + lan15;
            float eh = esqh_s[col];
            #pragma unroll
            for (int fr = 0; fr < 2; ++fr) {
                #pragma unroll
                for (int r = 0; r < 4; ++r) {
                    float u = eh - acc[fr][fc][r];
                    int s = fr * 4 + r;
                    second[s] = fminf(second[s], fmaxf(u, best[s]));
                    bidx[s] = (u < best[s]) ? col : bidx[s];
                    best[s] = fminf(u, best[s]);
                }
            }
        }
        __syncthreads();
    }

    // intra-wave reduce over 16-lane groups (lex: ties -> smaller col)
    #pragma unroll
    for (int s = 0; s < 8; ++s) {
        float b = best[s], sc = second[s];
        int bi = bidx[s];
        #pragma unroll
        for (int off = 1; off <= 8; off <<= 1) {
            float ob = __shfl_xor(b, off);
            float os = __shfl_xor(sc, off);
            int   oi = __shfl_xor(bi, off);
            float mx = fmaxf(b, ob);
            sc = fminf(fminf(sc, os), mx);
            if (ob < b) { b = ob; bi = oi; }
            else if (ob == b) bi = min(bi, oi);
        }
        best[s] = b; second[s] = sc; bidx[s] = bi;
    }
    if (lan15 == 0) {
        #pragma unroll
        for (int s = 0; s < 8; ++s) {
            int row = rg * 32 + (s >> 2) * 16 + (l >> 4) * 4 + (s & 3);
            cb_best[cg * BM + row] = best[s];
            cb_sec [cg * BM + row] = second[s];
            cb_idx [cg * BM + row] = bidx[s];
        }
    }
    __syncthreads();
    // cross-wave combine + flag emit (waves 0-1 fully active)
    if (t < BM) {
        float b0 = cb_best[t], b1 = cb_best[BM + t];
        float s0 = cb_sec[t],  s1 = cb_sec[BM + t];
        int   i0 = cb_idx[t],  i1 = cb_idx[BM + t];
        float b; int bi;
        if (b1 < b0 || (b1 == b0 && i1 < i0)) { b = b1; bi = i1; }
        else                                  { b = b0; bi = i0; }
        float sec = fminf(fminf(s0, s1), fmaxf(b0, b1));
        int gid = row0 + t;
        idx_out[gid] = (float)bi;
        bool flg = (sec - b <= EPS_U);
        fbi[t] = bi | (flg ? 0x80000000 : 0);
        unsigned long long mask = __ballot(flg);
        if (l == 0) bitmap[blockIdx.x * 2 + w] = mask;   // full-word, no init
        int nf = __popcll(mask);
        int base = 0;
        if (l == 0 && nf) base = atomicAdd(cnt, nf);
        base = __shfl(base, 0);
        if (flg) {
            int pos = __popcll(mask & ((1ull << l) - 1ull));
            wl[base + pos] = gid;
        }
    }
    __syncthreads();                 // fbi visible to all waves

    // ---- fused gather tail: z_q_st rows + per-block loss partial ----
    {
        const int tk = t >> 2, qd = t & 3;
        int pk = fbi[tk];
        int bi = pk & 0x3FF;
        bool fl = pk < 0;
        const float4* zr = (const float4*)z + (size_t)(row0 + tk) * 16 + qd * 4;
        const float4* er = (const float4*)E + (size_t)bi * 16 + qd * 4;
        float4* orow = (float4*)out0 + (size_t)(row0 + tk) * 16 + qd * 4;
        float ls = 0.f;
        #pragma unroll
        for (int j = 0; j < 4; ++j) {
            float4 zv = zr[j], ev = er[j];
            float dx = ev.x - zv.x, dy = ev.y - zv.y;
            float dz = ev.z - zv.z, dw = ev.w - zv.w;
            float4 o = {zv.x + dx, zv.y + dy, zv.z + dz, zv.w + dw};
            orow[j] = o;
            ls += dx * dx + dy * dy + dz * dz + dw * dw;
        }
        if (fl) ls = 0.f;            // flagged: exact contrib comes from fallback
        #pragma unroll
        for (int off = 1; off <= 32; off <<= 1) ls += __shfl_xor(ls, off);
        if (l == 0) wred[w] = ls;
    }
    __syncthreads();
    if (t == 0) {
        float s = 0.f;
        #pragma unroll
        for (int i = 0; i < 8; ++i) s += wred[i];
        partials[blockIdx.x] = s;
    }
}

// ------------- K2: exact recompute + repair for worklisted (near-tie) tokens
__global__ __launch_bounds__(256) void fallback_kernel(
    const float* __restrict__ z, const float* __restrict__ E,
    const float* __restrict__ esq_g, float* __restrict__ idx_out,
    float* __restrict__ out0, float* __restrict__ contrib,
    const int* __restrict__ wl, const int* __restrict__ cnt_p) {
    __shared__ __align__(16) float es[DIM][128];   // 32KB [k][code]
    __shared__ __align__(16) float zl[16][72];     // padded
    __shared__ float zqs[16];

    const int t = threadIdx.x;
    const int tg = t >> 4;           // token slot 0..15
    const int cs = t & 15;           // code slice (8 codes per tile)
    const int cnt = min(*cnt_p, NTOK);

    for (int chunk = blockIdx.x; chunk * 16 < cnt; chunk += 512) {
        const int base = chunk * 16;
        const int nval = min(16, cnt - base);
        const int tok = wl[base + (tg < nval ? tg : 0)];
        {
            float4 v = ((const float4*)z)[(size_t)tok * 16 + cs];
            *(float4*)&zl[tg][cs * 4] = v;
        }
        __syncthreads();
        if (t < 16) {                // zq per slot, sequential k (as R1)
            float s = 0.f;
            for (int k = 0; k < DIM; ++k) { float v = zl[t][k]; s += v * v; }
            zqs[t] = s;
        }
        __syncthreads();
        const float zq = zqs[tg];

        float best = 3.4e38f;
        int bi = 0;
        for (int tile = 0; tile < 8; ++tile) {   // ascending code tiles
            const float4* eg = (const float4*)(E + (size_t)tile * 128 * DIM);
            #pragma unroll
            for (int p = 0; p < 8; ++p) {        // R2 staging pattern verbatim
                int li = p * 256 + t;
                int c = li & 127, k4 = li >> 7;
                float4 v = eg[c * 16 + k4];
                es[k4 * 4 + 0][c] = v.x;
                es[k4 * 4 + 1][c] = v.y;
                es[k4 * 4 + 2][c] = v.z;
                es[k4 * 4 + 3][c] = v.w;
            }
            __syncthreads();

            float acc[8];
            #pragma unroll
            for (int n = 0; n < 8; ++n) acc[n] = 0.f;
            #pragma unroll 8
            for (int k = 0; k < DIM; ++k) {      // sequential fp32 FMA over K
                float a = zl[tg][k];
                float4 b0 = *(const float4*)&es[k][cs * 8 + 0];
                float4 b1 = *(const float4*)&es[k][cs * 8 + 4];
                float b[8] = {b0.x, b0.y, b0.z, b0.w, b1.x, b1.y, b1.z, b1.w};
                #pragma unroll
                for (int n = 0; n < 8; ++n) acc[n] += a * b[n];
            }
            #pragma unroll
            for (int n = 0; n < 8; ++n) {        // ascending code index, strict <
                int c = tile * 128 + cs * 8 + n;
                float d = (zq - 2.0f * acc[n]) + esq_g[c];
                if (d < best) { best = d; bi = c; }
            }
            __syncthreads();
        }
        #pragma unroll
        for (int off = 1; off <= 8; off <<= 1) {
            float ob = __shfl_xor(best, off);
            int   oi = __shfl_xor(bi, off);
            if (ob < best || (ob == best && oi < bi)) { best = ob; bi = oi; }
        }
        // repair: exact index, z_q_st row, per-token loss contribution
        if (tg < nval) {
            float4 zv = *(const float4*)&zl[tg][cs * 4];
            float4 ev = ((const float4*)E)[(size_t)bi * 16 + cs];
            float dx = ev.x - zv.x, dy = ev.y - zv.y;
            float dz = ev.z - zv.z, dw = ev.w - zv.w;
            float4 o = {zv.x + dx, zv.y + dy, zv.z + dz, zv.w + dw};
            ((float4*)out0)[(size_t)tok * 16 + cs] = o;
            float c4 = dx * dx + dy * dy + dz * dz + dw * dw;
            #pragma unroll
            for (int off = 1; off <= 8; off <<= 1) c4 += __shfl_xor(c4, off);
            if (cs == 0) {
                idx_out[tok] = (float)bi;
                contrib[tok] = c4;
            }
        }
        __syncthreads();
    }
}

// -------- K3: final loss = (sum partials + sum flagged contribs) scaled
__global__ __launch_bounds__(256) void loss_kernel(
    const float* __restrict__ partials, const unsigned long long* __restrict__ bitmap,
    const float* __restrict__ contrib, float* __restrict__ loss_out) {
    __shared__ float red[256];
    const int t = threadIdx.x;
    float p = 0.f;
    #pragma unroll
    for (int i = 0; i < 4; ++i) p += partials[t * 4 + i];
    for (int wi = t * 8; wi < t * 8 + 8; ++wi) {   // fixed token order per thread
        unsigned long long m = bitmap[wi];
        while (m) {
            int b = __builtin_ctzll(m);
            p += contrib[wi * 64 + b];
            m &= m - 1;
        }
    }
    red[t] = p;
    __syncthreads();
    for (int s = 128; s >= 1; s >>= 1) {
        if (t < s) red[t] += red[t + s];
        __syncthreads();
    }
    if (t == 0) {
        float m = red[0] / (float)(NTOK * DIM);
        loss_out[0] = m + 0.25f * m;
    }
}

extern "C" void kernel_launch(void* const* d_in, const int* in_sizes, int n_in,
                              void* d_out, int out_size, void* d_ws, size_t ws_size,
                              hipStream_t stream) {
    const float* z = (const float*)d_in[0];       // [131072, 64] f32
    const float* E = (const float*)d_in[1];       // [1024, 64] f32
    float* out = (float*)d_out;

    char* wsb = (char*)d_ws;
    float*              esq      = (float*)(wsb);               // 4 KB
    float*              esqh     = (float*)(wsb + 4096);        // 4 KB
    float*              partials = (float*)(wsb + 8192);        // 8 KB (1024 used)
    int*                cnt      = (int*)(wsb + 16384);         // 4 KB region
    int*                wl       = (int*)(wsb + 20480);         // 128 KB
    unsigned long long* bitmap   = (unsigned long long*)(wsb + 151552); // 16 KB
    unsigned short*     Bswz     = (unsigned short*)(wsb + 167936);     // 256 KB
    float*              contrib  = (float*)(wsb + 430080);      // 512 KB

    prep_kernel<<<256, 256, 0, stream>>>(E, Bswz, esqh, esq, cnt);
    mfma_argmin_kernel<<<NTOK / BM, 512, 0, stream>>>(z, E, Bswz, esqh,
                                                      out + IDX_OFF, out,
                                                      partials, cnt, wl, bitmap);
    fallback_kernel<<<512, 256, 0, stream>>>(z, E, esq, out + IDX_OFF, out,
                                             contrib, wl, cnt);
    loss_kernel<<<1, 256, 0, stream>>>(partials, bitmap, contrib, out + LOSS_OFF);
}

// Round 12
// 145.469 us; speedup vs baseline: 2.2432x; 1.0431x over previous
//
#include <hip/hip_runtime.h>

#define NTOK   131072
#define KCODES 1024
#define DIM    64
#define BM     128
#define BN     64
#define NCT    (KCODES / BN)         // 16 code tiles
#define SLOT_CAP 16384               // worklist capacity (cnt ~5.3K observed)

#define LOSS_OFF (NTOK * DIM)        // 8388608
#define IDX_OFF  (LOSS_OFF + 1)      // 8388609

#define EPS_U 6e-5f                  // u-metric gap threshold (d-gap = 2u)

typedef __attribute__((ext_vector_type(8))) short bf16x8;
typedef __attribute__((ext_vector_type(4))) float f32x4;
typedef __attribute__((ext_vector_type(4))) unsigned short ush4;

#if defined(__has_builtin)
#if __has_builtin(__builtin_amdgcn_global_load_lds)
#define HAVE_GLD 1
#endif
#endif

#ifdef HAVE_GLD
typedef const __attribute__((address_space(1))) unsigned int* gas_u32p;
typedef __attribute__((address_space(3))) unsigned int* las_u32p;
#define GLD16(ldst, gsrc) \
    __builtin_amdgcn_global_load_lds((gas_u32p)(gsrc), (las_u32p)(ldst), 16, 0, 0)
#endif

__device__ inline unsigned short bf16rtn(float x) {
    unsigned u = __float_as_uint(x);
    return (unsigned short)((u + 0x7fffu + ((u >> 16) & 1u)) >> 16);
}

// monotone float->u32 map (total order == float order; -0 can't occur here),
// packed with idx so u64-min == lexicographic (d, idx) min.
__device__ inline unsigned long long packdi(float d, int idx) {
    unsigned b = __float_as_uint(d);
    b ^= (b & 0x80000000u) ? 0xFFFFFFFFu : 0x80000000u;
    return ((unsigned long long)b << 32) | (unsigned)idx;
}

// ---- K0: split E -> bf16 hi|lo PRE-SWIZZLED per-tile layout, esq, clear cnt
__global__ __launch_bounds__(256) void prep_kernel(const float* __restrict__ E,
                                                   unsigned short* __restrict__ Bswz,
                                                   float* __restrict__ esqh,
                                                   float* __restrict__ esq,
                                                   int* __restrict__ cnt) {
    const int t = threadIdx.x, b = blockIdx.x;
    if (b == 0 && t == 0) cnt[0] = 0;
    int id = b * 256 + t;                      // 65536 = 1024 x 64
    int c = id >> 6, k = id & 63;
    float x = E[id];
    unsigned short h = bf16rtn(x);
    float hf = __uint_as_float(((unsigned)h) << 16);
    unsigned short lo = bf16rtn(x - hf);
    int rx = (c & 7) << 4;
    int qh = (k >> 3) << 4;                    // 16B chunk byte offset
    int ob = (k & 7) << 1;                     // byte within chunk
    Bswz[(c * 256 + (qh ^ rx) + ob) >> 1]           = h;
    Bswz[(c * 256 + ((128 + qh) ^ rx) + ob) >> 1]   = lo;
    if (b < 4) {                               // esq: arithmetic verbatim (R1-R11)
        int cc = b * 256 + t;
        const float4* row = (const float4*)(E + cc * DIM);
        float s = 0.f;
        #pragma unroll
        for (int i = 0; i < DIM / 4; ++i) {
            float4 v = row[i];
            s += v.x * v.x + v.y * v.y + v.z * v.z + v.w * v.w;
        }
        esq[cc] = s;
        esqh[cc] = 0.5f * s;                   // exact
    }
}

// ------------------------------------------------- K1: MFMA distances + argmin
// As R11: 512 thr, A-hi regs / A-lo LDS, dbuf Bs via global_load_lds, fused
// gather tail + per-block loss partial + bitmap/worklist flag emit.
__global__ __launch_bounds__(512, 4) void mfma_argmin_kernel(
    const float* __restrict__ z, const float* __restrict__ E,
    const unsigned short* __restrict__ Bswz, const float* __restrict__ esqh_g,
    float* __restrict__ idx_out, float* __restrict__ out0,
    float* __restrict__ partials, int* __restrict__ cnt, int* __restrict__ wl,
    unsigned long long* __restrict__ bitmap) {
    // [0,16K): A-hi then Bs0 | [16K,32K): A-lo (live) | [32K,48K): Bs1
    __shared__ __align__(16) char lds[49152];
    __shared__ __align__(16) char aux[4096];
    float* esqh_s  = (float*)aux;              // dead after main loop
    float* cb_best = (float*)aux;              // [2][128]
    float* cb_sec  = (float*)(aux + 1024);
    int*   cb_idx  = (int*)(aux + 2048);
    int*   fbi     = (int*)(aux + 3072);       // [128] packed idx|flag
    float* wred    = (float*)(aux + 3584);     // [8]

    const int t = threadIdx.x;
    const int l = t & 63;
    const int w = t >> 6;            // wave 0..7
    const int rg = w >> 1;           // row group (32 tokens)
    const int cg = w & 1;            // col group (32 codes)
    const int lan15 = l & 15;
    const int kp16 = (l >> 4) * 16;
    const int xr = (lan15 & 7) << 4;
    const int row0 = blockIdx.x * BM;
    const char* gb = (const char*)Bswz;
    const int goff = w * 2048 + l * 16;

    // issue tile0 -> Bs1 immediately (hides under prologue)
#ifdef HAVE_GLD
    GLD16(lds + 32768 + w * 2048,        gb + goff);
    GLD16(lds + 32768 + w * 2048 + 1024, gb + goff + 1024);
#else
    uint4 pv0a = *(const uint4*)(gb + goff);
    uint4 pv0b = *(const uint4*)(gb + goff + 1024);
#endif

    esqh_s[t]       = esqh_g[t];
    esqh_s[512 + t] = esqh_g[512 + t];

    // z load + hi/lo split -> A-hi [0,16K), A-lo [16K,32K)
    {
        const float4* zg = (const float4*)(z + (size_t)row0 * DIM);
        float4 av[4];
        #pragma unroll
        for (int p = 0; p < 4; ++p) av[p] = zg[p * 512 + t];
        #pragma unroll
        for (int p = 0; p < 4; ++p) {
            int li = p * 512 + t;
            int r = li >> 4, q = li & 15;
            float xs[4] = {av[p].x, av[p].y, av[p].z, av[p].w};
            ush4 hv, lv;
            #pragma unroll
            for (int j = 0; j < 4; ++j) {
                unsigned short h = bf16rtn(xs[j]);
                float hf = __uint_as_float(((unsigned)h) << 16);
                hv[j] = h;
                lv[j] = bf16rtn(xs[j] - hf);
            }
            int rxw = (r & 7) << 4;
            int o = ((q * 8) ^ rxw);
            *(ush4*)(lds + r * 128 + o)         = hv;
            *(ush4*)(lds + 16384 + r * 128 + o) = lv;
        }
    }
#ifndef HAVE_GLD
    *(uint4*)(lds + 32768 + goff)        = pv0a;
    *(uint4*)(lds + 32768 + goff + 1024) = pv0b;
#endif
    __syncthreads();

    const int ko0 = kp16 ^ xr;
    const int ko1 = (64 + kp16) ^ xr;
    const int arow = (rg * 32 + lan15) * 128;
    const char* alo = lds + 16384 + arow;

    bf16x8 ah00 = *(const bf16x8*)(lds + arow + ko0);
    bf16x8 ah01 = *(const bf16x8*)(lds + arow + ko1);
    bf16x8 ah10 = *(const bf16x8*)(lds + arow + 2048 + ko0);
    bf16x8 ah11 = *(const bf16x8*)(lds + arow + 2048 + ko1);
    __syncthreads();                 // A-hi reads done; tile0 drained

    float best[8], second[8];
    int   bidx[8];
    #pragma unroll
    for (int s = 0; s < 8; ++s) { best[s] = 3.4e38f; second[s] = 3.4e38f; bidx[s] = 0; }

    const int brow = (cg * 32 + lan15) * 256;

    for (int ct = 0; ct < NCT; ++ct) {
        char* cur = lds + ((ct & 1) ^ 1) * 32768;
        if (ct < NCT - 1) {
            char* nbuf = lds + (ct & 1) * 32768;
            const char* g = gb + (ct + 1) * 16384 + goff;
#ifdef HAVE_GLD
            GLD16(nbuf + w * 2048,        g);
            GLD16(nbuf + w * 2048 + 1024, g + 1024);
#else
            *(uint4*)(nbuf + goff)        = *(const uint4*)(g);
            *(uint4*)(nbuf + goff + 1024) = *(const uint4*)(g + 1024);
#endif
        }

        f32x4 acc[2][2];
        #pragma unroll
        for (int fr = 0; fr < 2; ++fr)
            #pragma unroll
            for (int fc = 0; fc < 2; ++fc)
                acc[fr][fc] = (f32x4){0.f, 0.f, 0.f, 0.f};

        #pragma unroll
        for (int fc = 0; fc < 2; ++fc) {
            const char* bp = cur + brow + fc * 4096;
            bf16x8 b0 = *(const bf16x8*)(bp + ko0);
            bf16x8 b1 = *(const bf16x8*)(bp + ko1);
            acc[0][fc] = __builtin_amdgcn_mfma_f32_16x16x32_bf16(ah00, b0, acc[0][fc], 0, 0, 0);
            acc[1][fc] = __builtin_amdgcn_mfma_f32_16x16x32_bf16(ah10, b0, acc[1][fc], 0, 0, 0);
            acc[0][fc] = __builtin_amdgcn_mfma_f32_16x16x32_bf16(ah01, b1, acc[0][fc], 0, 0, 0);
            acc[1][fc] = __builtin_amdgcn_mfma_f32_16x16x32_bf16(ah11, b1, acc[1][fc], 0, 0, 0);
            {
                bf16x8 al0 = *(const bf16x8*)(alo + ko0);
                bf16x8 al1 = *(const bf16x8*)(alo + 2048 + ko0);
                acc[0][fc] = __builtin_amdgcn_mfma_f32_16x16x32_bf16(al0, b0, acc[0][fc], 0, 0, 0);
                acc[1][fc] = __builtin_amdgcn_mfma_f32_16x16x32_bf16(al1, b0, acc[1][fc], 0, 0, 0);
            }
            {
                bf16x8 al2 = *(const bf16x8*)(alo + ko1);
                bf16x8 al3 = *(const bf16x8*)(alo + 2048 + ko1);
                acc[0][fc] = __builtin_amdgcn_mfma_f32_16x16x32_bf16(al2, b1, acc[0][fc], 0, 0, 0);
                acc[1][fc] = __builtin_amdgcn_mfma_f32_16x16x32_bf16(al3, b1, acc[1][fc], 0, 0, 0);
            }
            {
                bf16x8 b2 = *(const bf16x8*)(bp + 128 + ko0);
                acc[0][fc] = __builtin_amdgcn_mfma_f32_16x16x32_bf16(ah00, b2, acc[0][fc], 0, 0, 0);
                acc[1][fc] = __builtin_amdgcn_mfma_f32_16x16x32_bf16(ah10, b2, acc[1][fc], 0, 0, 0);
            }
            {
                bf16x8 b3 = *(const bf16x8*)(bp + 128 + ko1);
                acc[0][fc] = __builtin_amdgcn_mfma_f32_16x16x32_bf16(ah01, b3, acc[0][fc], 0, 0, 0);
                acc[1][fc] = __builtin_amdgcn_mfma_f32_16x16x32_bf16(ah11, b3, acc[1][fc], 0, 0, 0);
            }
        }

        #pragma unroll
        for (int fc = 0; fc < 2; ++fc) {
            int col = ct * BN + cg * 32 + fc * 16 + lan15;
            float eh = esqh_s[col];
            #pragma unroll
            for (int fr = 0; fr < 2; ++fr) {
                #pragma unroll
                for (int r = 0; r < 4; ++r) {
                    float u = eh - acc[fr][fc][r];
                    int s = fr * 4 + r;
                    second[s] = fminf(second[s], fmaxf(u, best[s]));
                    bidx[s] = (u < best[s]) ? col : bidx[s];
                    best[s] = fminf(u, best[s]);
                }
            }
        }
        __syncthreads();
    }

    // intra-wave reduce over 16-lane groups (lex: ties -> smaller col)
    #pragma unroll
    for (int s = 0; s < 8; ++s) {
        float b = best[s], sc = second[s];
        int bi = bidx[s];
        #pragma unroll
        for (int off = 1; off <= 8; off <<= 1) {
            float ob = __shfl_xor(b, off);
            float os = __shfl_xor(sc, off);
            int   oi = __shfl_xor(bi, off);
            float mx = fmaxf(b, ob);
            sc = fminf(fminf(sc, os), mx);
            if (ob < b) { b = ob; bi = oi; }
            else if (ob == b) bi = min(bi, oi);
        }
        best[s] = b; second[s] = sc; bidx[s] = bi;
    }
    if (lan15 == 0) {
        #pragma unroll
        for (int s = 0; s < 8; ++s) {
            int row = rg * 32 + (s >> 2) * 16 + (l >> 4) * 4 + (s & 3);
            cb_best[cg * BM + row] = best[s];
            cb_sec [cg * BM + row] = second[s];
            cb_idx [cg * BM + row] = bidx[s];
        }
    }
    __syncthreads();
    // cross-wave combine + flag emit
    if (t < BM) {
        float b0 = cb_best[t], b1 = cb_best[BM + t];
        float s0 = cb_sec[t],  s1 = cb_sec[BM + t];
        int   i0 = cb_idx[t],  i1 = cb_idx[BM + t];
        float b; int bi;
        if (b1 < b0 || (b1 == b0 && i1 < i0)) { b = b1; bi = i1; }
        else                                  { b = b0; bi = i0; }
        float sec = fminf(fminf(s0, s1), fmaxf(b0, b1));
        int gid = row0 + t;
        idx_out[gid] = (float)bi;
        bool flg = (sec - b <= EPS_U);
        fbi[t] = bi | (flg ? 0x80000000 : 0);
        unsigned long long mask = __ballot(flg);
        if (l == 0) bitmap[blockIdx.x * 2 + w] = mask;   // full-word, no init
        int nf = __popcll(mask);
        int base = 0;
        if (l == 0 && nf) base = atomicAdd(cnt, nf);
        base = __shfl(base, 0);
        if (flg) {
            int pos = __popcll(mask & ((1ull << l) - 1ull));
            int slot = base + pos;
            if (slot < SLOT_CAP) wl[slot] = gid;
        }
    }
    __syncthreads();                 // fbi visible to all waves

    // ---- fused gather tail: z_q_st rows + per-block loss partial ----
    {
        const int tk = t >> 2, qd = t & 3;
        int pk = fbi[tk];
        int bi = pk & 0x3FF;
        bool fl = pk < 0;
        const float4* zr = (const float4*)z + (size_t)(row0 + tk) * 16 + qd * 4;
        const float4* er = (const float4*)E + (size_t)bi * 16 + qd * 4;
        float4* orow = (float4*)out0 + (size_t)(row0 + tk) * 16 + qd * 4;
        float ls = 0.f;
        #pragma unroll
        for (int j = 0; j < 4; ++j) {
            float4 zv = zr[j], ev = er[j];
            float dx = ev.x - zv.x, dy = ev.y - zv.y;
            float dz = ev.z - zv.z, dw = ev.w - zv.w;
            float4 o = {zv.x + dx, zv.y + dy, zv.z + dz, zv.w + dw};
            orow[j] = o;
            ls += dx * dx + dy * dy + dz * dz + dw * dw;
        }
        if (fl) ls = 0.f;            // flagged: exact contrib comes from repair
        #pragma unroll
        for (int off = 1; off <= 32; off <<= 1) ls += __shfl_xor(ls, off);
        if (l == 0) wred[w] = ls;
    }
    __syncthreads();
    if (t == 0) {
        float s = 0.f;
        #pragma unroll
        for (int i = 0; i < 8; ++i) s += wred[i];
        partials[blockIdx.x] = s;
    }
}

// ---- K2: exact recompute, QUARTER-SPLIT: block (chunk, qtr) scans 256 codes
// for 16 worklisted tokens; emits packed (d,idx) candidate per (token,qtr).
// Staging + FMA chain byte-identical to the R2-pedigree exact scan.
__global__ __launch_bounds__(256) void fallback_kernel(
    const float* __restrict__ z, const float* __restrict__ E,
    const float* __restrict__ esq_g, unsigned long long* __restrict__ cand,
    const int* __restrict__ wl, const int* __restrict__ cnt_p) {
    __shared__ __align__(16) float es[DIM][128];   // 32KB [k][code]
    __shared__ __align__(16) float zl[16][72];     // padded
    __shared__ float zqs[16];

    const int t = threadIdx.x;
    const int tg = t >> 4;           // token slot 0..15
    const int cs = t & 15;           // code slice (8 codes per tile)
    const int cnt = min(*cnt_p, SLOT_CAP);
    const int nwork = ((cnt + 15) >> 4) << 2;      // chunks * 4 quarters

    for (int cb = blockIdx.x; cb < nwork; cb += 2048) {
        const int chunk = cb >> 2, qtr = cb & 3;
        const int base = chunk * 16;
        const int nval = min(16, cnt - base);
        const int tok = wl[base + (tg < nval ? tg : 0)];
        {
            float4 v = ((const float4*)z)[(size_t)tok * 16 + cs];
            *(float4*)&zl[tg][cs * 4] = v;
        }
        __syncthreads();
        if (t < 16) {                // zq per slot, sequential k (as R1)
            float s = 0.f;
            for (int k = 0; k < DIM; ++k) { float v = zl[t][k]; s += v * v; }
            zqs[t] = s;
        }
        __syncthreads();
        const float zq = zqs[tg];

        float best = 3.4e38f;
        int bi = 0;
        for (int ti = 0; ti < 2; ++ti) {         // 2 tiles of this quarter
            const int tile = qtr * 2 + ti;
            const float4* eg = (const float4*)(E + (size_t)tile * 128 * DIM);
            #pragma unroll
            for (int p = 0; p < 8; ++p) {        // R2 staging pattern verbatim
                int li = p * 256 + t;
                int c = li & 127, k4 = li >> 7;
                float4 v = eg[c * 16 + k4];
                es[k4 * 4 + 0][c] = v.x;
                es[k4 * 4 + 1][c] = v.y;
                es[k4 * 4 + 2][c] = v.z;
                es[k4 * 4 + 3][c] = v.w;
            }
            __syncthreads();

            float acc[8];
            #pragma unroll
            for (int n = 0; n < 8; ++n) acc[n] = 0.f;
            #pragma unroll 8
            for (int k = 0; k < DIM; ++k) {      // sequential fp32 FMA over K
                float a = zl[tg][k];
                float4 b0 = *(const float4*)&es[k][cs * 8 + 0];
                float4 b1 = *(const float4*)&es[k][cs * 8 + 4];
                float b[8] = {b0.x, b0.y, b0.z, b0.w, b1.x, b1.y, b1.z, b1.w};
                #pragma unroll
                for (int n = 0; n < 8; ++n) acc[n] += a * b[n];
            }
            #pragma unroll
            for (int n = 0; n < 8; ++n) {        // ascending code index, strict <
                int c = tile * 128 + cs * 8 + n;
                float d = (zq - 2.0f * acc[n]) + esq_g[c];
                if (d < best) { best = d; bi = c; }
            }
            __syncthreads();
        }
        // lex-min over the 16 lanes of this token group
        #pragma unroll
        for (int off = 1; off <= 8; off <<= 1) {
            float ob = __shfl_xor(best, off);
            int   oi = __shfl_xor(bi, off);
            if (ob < best || (ob == best && oi < bi)) { best = ob; bi = oi; }
        }
        if (cs == 0 && tg < nval)
            cand[(size_t)(base + tg) * 4 + qtr] = packdi(best, bi);
        __syncthreads();
    }
}

// ---- K3: repair flagged tokens: u64-min of 4 quarter candidates (== lex-min
// over all 1024 codes), write exact idx + z_q_st row + per-token contrib.
__global__ __launch_bounds__(256) void repair_kernel(
    const float* __restrict__ z, const float* __restrict__ E,
    float* __restrict__ idx_out, float* __restrict__ out0,
    float* __restrict__ contrib, const unsigned long long* __restrict__ cand,
    const int* __restrict__ wl, const int* __restrict__ cnt_p) {
    const int t = threadIdx.x;
    const int tg = t >> 4;           // token slot 0..15
    const int cs = t & 15;           // float4 chunk of dim
    const int cnt = min(*cnt_p, SLOT_CAP);

    for (int s0 = blockIdx.x * 16; s0 < cnt; s0 += 512 * 16) {
        int s = s0 + tg;
        if (s < cnt) {
            int tok = wl[s];
            unsigned long long m = cand[(size_t)s * 4 + 0];
            m = min(m, cand[(size_t)s * 4 + 1]);
            m = min(m, cand[(size_t)s * 4 + 2]);
            m = min(m, cand[(size_t)s * 4 + 3]);
            int bi = (int)(unsigned)(m & 0xFFFFFFFFull);
            float4 zv = ((const float4*)z)[(size_t)tok * 16 + cs];
            float4 ev = ((const float4*)E)[(size_t)bi * 16 + cs];
            float dx = ev.x - zv.x, dy = ev.y - zv.y;
            float dz = ev.z - zv.z, dw = ev.w - zv.w;
            float4 o = {zv.x + dx, zv.y + dy, zv.z + dz, zv.w + dw};
            ((float4*)out0)[(size_t)tok * 16 + cs] = o;
            float c4 = dx * dx + dy * dy + dz * dz + dw * dw;
            #pragma unroll
            for (int off = 1; off <= 8; off <<= 1) c4 += __shfl_xor(c4, off);
            if (cs == 0) {
                idx_out[tok] = (float)bi;
                contrib[tok] = c4;
            }
        }
    }
}

// -------- K4: final loss = (sum partials + sum flagged contribs) scaled
__global__ __launch_bounds__(256) void loss_kernel(
    const float* __restrict__ partials, const unsigned long long* __restrict__ bitmap,
    const float* __restrict__ contrib, float* __restrict__ loss_out) {
    __shared__ float red[256];
    const int t = threadIdx.x;
    float p = 0.f;
    #pragma unroll
    for (int i = 0; i < 4; ++i) p += partials[t * 4 + i];
    for (int wi = t * 8; wi < t * 8 + 8; ++wi) {   // fixed token order per thread
        unsigned long long m = bitmap[wi];
        while (m) {
            int b = __builtin_ctzll(m);
            p += contrib[wi * 64 + b];
            m &= m - 1;
        }
    }
    red[t] = p;
    __syncthreads();
    for (int s = 128; s >= 1; s >>= 1) {
        if (t < s) red[t] += red[t + s];
        __syncthreads();
    }
    if (t == 0) {
        float m = red[0] / (float)(NTOK * DIM);
        loss_out[0] = m + 0.25f * m;
    }
}

extern "C" void kernel_launch(void* const* d_in, const int* in_sizes, int n_in,
                              void* d_out, int out_size, void* d_ws, size_t ws_size,
                              hipStream_t stream) {
    const float* z = (const float*)d_in[0];       // [131072, 64] f32
    const float* E = (const float*)d_in[1];       // [1024, 64] f32
    float* out = (float*)d_out;

    char* wsb = (char*)d_ws;
    float*              esq      = (float*)(wsb);               // 4 KB
    float*              esqh     = (float*)(wsb + 4096);        // 4 KB
    float*              partials = (float*)(wsb + 8192);        // 8 KB (1024 used)
    int*                cnt      = (int*)(wsb + 16384);         // 4 KB region
    int*                wl       = (int*)(wsb + 20480);         // 64 KB
    unsigned long long* bitmap   = (unsigned long long*)(wsb + 86016);  // 16 KB
    unsigned short*     Bswz     = (unsigned short*)(wsb + 102400);     // 256 KB
    float*              contrib  = (float*)(wsb + 364544);      // 512 KB
    unsigned long long* cand     = (unsigned long long*)(wsb + 888832); // 512 KB

    prep_kernel<<<256, 256, 0, stream>>>(E, Bswz, esqh, esq, cnt);
    mfma_argmin_kernel<<<NTOK / BM, 512, 0, stream>>>(z, E, Bswz, esqh,
                                                      out + IDX_OFF, out,
                                                      partials, cnt, wl, bitmap);
    fallback_kernel<<<2048, 256, 0, stream>>>(z, E, esq, cand, wl, cnt);
    repair_kernel<<<512, 256, 0, stream>>>(z, E, out + IDX_OFF, out, contrib,
                                           cand, wl, cnt);
    loss_kernel<<<1, 256, 0, stream>>>(partials, bitmap, contrib, out + LOSS_OFF);
}

// Round 13
// 119.990 us; speedup vs baseline: 2.7195x; 1.2123x over previous
//
#include <hip/hip_runtime.h>

#define NTOK   131072
#define KCODES 1024
#define DIM    64
#define BM     128
#define BN     128
#define NCT    (KCODES / BN)         // 8 code tiles
#define SLOT_CAP 16384               // worklist capacity

#define LOSS_OFF (NTOK * DIM)        // 8388608
#define IDX_OFF  (LOSS_OFF + 1)      // 8388609

#define EPS_U 3e-5f                  // u-gap threshold; worst-case err ~4e-6 -> 7.5x margin

typedef __attribute__((ext_vector_type(8))) short bf16x8;
typedef __attribute__((ext_vector_type(4))) float f32x4;
typedef __attribute__((ext_vector_type(4))) unsigned short ush4;

#if defined(__has_builtin)
#if __has_builtin(__builtin_amdgcn_global_load_lds)
#define HAVE_GLD 1
#endif
#endif

#ifdef HAVE_GLD
typedef const __attribute__((address_space(1))) unsigned int* gas_u32p;
typedef __attribute__((address_space(3))) unsigned int* las_u32p;
#define GLD16(ldst, gsrc) \
    __builtin_amdgcn_global_load_lds((gas_u32p)(gsrc), (las_u32p)(ldst), 16, 0, 0)
#endif

__device__ inline unsigned short bf16rtn(float x) {
    unsigned u = __float_as_uint(x);
    return (unsigned short)((u + 0x7fffu + ((u >> 16) & 1u)) >> 16);
}

// monotone float->u32 map; packed with idx so u64-min == lex (d, idx) min.
__device__ inline unsigned long long packdi(float d, int idx) {
    unsigned b = __float_as_uint(d);
    b ^= (b & 0x80000000u) ? 0xFFFFFFFFu : 0x80000000u;
    return ((unsigned long long)b << 32) | (unsigned)idx;
}

// ---- K0: split E -> bf16 hi|lo PRE-SWIZZLED per-code-row layout, esq, clear cnt
__global__ __launch_bounds__(256) void prep_kernel(const float* __restrict__ E,
                                                   unsigned short* __restrict__ Bswz,
                                                   float* __restrict__ esqh,
                                                   float* __restrict__ esq,
                                                   int* __restrict__ cnt) {
    const int t = threadIdx.x, b = blockIdx.x;
    if (b == 0 && t == 0) cnt[0] = 0;
    int id = b * 256 + t;                      // 65536 = 1024 x 64
    int c = id >> 6, k = id & 63;
    float x = E[id];
    unsigned short h = bf16rtn(x);
    float hf = __uint_as_float(((unsigned)h) << 16);
    unsigned short lo = bf16rtn(x - hf);
    int rx = (c & 7) << 4;
    int qh = (k >> 3) << 4;                    // 16B chunk byte offset
    int ob = (k & 7) << 1;                     // byte within chunk
    Bswz[(c * 256 + (qh ^ rx) + ob) >> 1]           = h;
    Bswz[(c * 256 + ((128 + qh) ^ rx) + ob) >> 1]   = lo;
    if (b < 4) {                               // esq: arithmetic verbatim (R1-R12)
        int cc = b * 256 + t;
        const float4* row = (const float4*)(E + cc * DIM);
        float s = 0.f;
        #pragma unroll
        for (int i = 0; i < DIM / 4; ++i) {
            float4 v = row[i];
            s += v.x * v.x + v.y * v.y + v.z * v.z + v.w * v.w;
        }
        esq[cc] = s;
        esqh[cc] = 0.5f * s;                   // exact
    }
}

// ------------------------------------------------- K1: MFMA distances + argmin
// 512 thr = 8 waves (4 rg x 2 cg); wave tile 32 tok x 64 codes (fr=2 x fc=4);
// BN=128 -> 8 code tiles, ONE barrier each. All 8 A-frags (hi+lo) ct-invariant
// in regs. B staged by global_load_lds from pre-swizzled global into 2x32KB
// dbuf (Bs0 overlays dead A-staging). Fused gather tail + loss partial + flags.
__global__ __launch_bounds__(512, 4) void mfma_argmin_kernel(
    const float* __restrict__ z, const float* __restrict__ E,
    const unsigned short* __restrict__ Bswz, const float* __restrict__ esqh_g,
    float* __restrict__ idx_out, float* __restrict__ out0,
    float* __restrict__ partials, int* __restrict__ cnt, int* __restrict__ wl,
    unsigned long long* __restrict__ bitmap) {
    // [0,32K): A-hi/A-lo staging, then Bs0 | [32K,64K): Bs1
    __shared__ __align__(16) char lds[65536];
    __shared__ __align__(16) char aux[4096];
    float* esqh_s  = (float*)aux;              // dead after main loop
    float* cb_best = (float*)aux;              // [2][128]
    float* cb_sec  = (float*)(aux + 1024);
    int*   cb_idx  = (int*)(aux + 2048);
    int*   fbi     = (int*)(aux + 3072);       // [128] packed idx|flag
    float* wred    = (float*)(aux + 3584);     // [8]

    const int t = threadIdx.x;
    const int l = t & 63;
    const int w = t >> 6;            // wave 0..7
    const int rg = w >> 1;           // row group (32 tokens)
    const int cg = w & 1;            // col group (64 codes)
    const int lan15 = l & 15;
    const int kp16 = (l >> 4) * 16;
    const int xr = (lan15 & 7) << 4;
    const int row0 = blockIdx.x * BM;
    const char* gb = (const char*)Bswz;

    // issue tile0 -> Bs1 [32K,64K) immediately (hides under prologue)
#ifdef HAVE_GLD
    #pragma unroll
    for (int p = 0; p < 4; ++p)
        GLD16(lds + 32768 + p * 8192 + t * 16, gb + p * 8192 + t * 16);
#else
    uint4 pv0[4];
    #pragma unroll
    for (int p = 0; p < 4; ++p)
        pv0[p] = *(const uint4*)(gb + p * 8192 + t * 16);
#endif

    esqh_s[t]       = esqh_g[t];
    esqh_s[512 + t] = esqh_g[512 + t];

    // z load + hi/lo split -> A-hi [0,16K), A-lo [16K,32K)
    {
        const float4* zg = (const float4*)(z + (size_t)row0 * DIM);
        float4 av[4];
        #pragma unroll
        for (int p = 0; p < 4; ++p) av[p] = zg[p * 512 + t];
        #pragma unroll
        for (int p = 0; p < 4; ++p) {
            int li = p * 512 + t;
            int r = li >> 4, q = li & 15;
            float xs[4] = {av[p].x, av[p].y, av[p].z, av[p].w};
            ush4 hv, lv;
            #pragma unroll
            for (int j = 0; j < 4; ++j) {
                unsigned short h = bf16rtn(xs[j]);
                float hf = __uint_as_float(((unsigned)h) << 16);
                hv[j] = h;
                lv[j] = bf16rtn(xs[j] - hf);
            }
            int rxw = (r & 7) << 4;
            int o = ((q * 8) ^ rxw);
            *(ush4*)(lds + r * 128 + o)         = hv;
            *(ush4*)(lds + 16384 + r * 128 + o) = lv;
        }
    }
#ifndef HAVE_GLD
    #pragma unroll
    for (int p = 0; p < 4; ++p)
        *(uint4*)(lds + 32768 + p * 8192 + t * 16) = pv0[p];
#endif
    __syncthreads();

    const int ko0 = kp16 ^ xr;
    const int ko1 = (64 + kp16) ^ xr;
    const int arow = (rg * 32 + lan15) * 128;

    // all 8 A fragments ct-invariant -> registers (32 VGPR)
    bf16x8 ah00 = *(const bf16x8*)(lds + arow + ko0);
    bf16x8 ah01 = *(const bf16x8*)(lds + arow + ko1);
    bf16x8 ah10 = *(const bf16x8*)(lds + arow + 2048 + ko0);
    bf16x8 ah11 = *(const bf16x8*)(lds + arow + 2048 + ko1);
    bf16x8 al00 = *(const bf16x8*)(lds + 16384 + arow + ko0);
    bf16x8 al01 = *(const bf16x8*)(lds + 16384 + arow + ko1);
    bf16x8 al10 = *(const bf16x8*)(lds + 16384 + arow + 2048 + ko0);
    bf16x8 al11 = *(const bf16x8*)(lds + 16384 + arow + 2048 + ko1);
    __syncthreads();                 // A reads done; [0,32K) free; tile0 drained

    float best[8], second[8];
    int   bidx[8];
    #pragma unroll
    for (int s = 0; s < 8; ++s) { best[s] = 3.4e38f; second[s] = 3.4e38f; bidx[s] = 0; }

    const int brow = (cg * 64 + lan15) * 256;  // + fc*4096 (imm)

    for (int ct = 0; ct < NCT; ++ct) {
        // cur: ct even -> Bs1 [32K), odd -> Bs0 [0); prefetch into the other
        char* cur = lds + ((ct & 1) ^ 1) * 32768;
        if (ct < NCT - 1) {
            char* nbuf = lds + (ct & 1) * 32768;
            const char* g = gb + (size_t)(ct + 1) * 32768;
#ifdef HAVE_GLD
            #pragma unroll
            for (int p = 0; p < 4; ++p)
                GLD16(nbuf + p * 8192 + t * 16, g + p * 8192 + t * 16);
#else
            #pragma unroll
            for (int p = 0; p < 4; ++p)
                *(uint4*)(nbuf + p * 8192 + t * 16) =
                    *(const uint4*)(g + p * 8192 + t * 16);
#endif
        }

        f32x4 acc[2][4];
        #pragma unroll
        for (int fr = 0; fr < 2; ++fr)
            #pragma unroll
            for (int fc = 0; fc < 4; ++fc)
                acc[fr][fc] = (f32x4){0.f, 0.f, 0.f, 0.f};

        // per-acc term order FP-identical to R6-R12: hh,hh,lh,lh,hl,hl
        #pragma unroll
        for (int fc = 0; fc < 4; ++fc) {
            const char* bp = cur + brow + fc * 4096;
            bf16x8 b0 = *(const bf16x8*)(bp + ko0);
            bf16x8 b1 = *(const bf16x8*)(bp + ko1);
            acc[0][fc] = __builtin_amdgcn_mfma_f32_16x16x32_bf16(ah00, b0, acc[0][fc], 0, 0, 0);
            acc[1][fc] = __builtin_amdgcn_mfma_f32_16x16x32_bf16(ah10, b0, acc[1][fc], 0, 0, 0);
            acc[0][fc] = __builtin_amdgcn_mfma_f32_16x16x32_bf16(ah01, b1, acc[0][fc], 0, 0, 0);
            acc[1][fc] = __builtin_amdgcn_mfma_f32_16x16x32_bf16(ah11, b1, acc[1][fc], 0, 0, 0);
            acc[0][fc] = __builtin_amdgcn_mfma_f32_16x16x32_bf16(al00, b0, acc[0][fc], 0, 0, 0);
            acc[1][fc] = __builtin_amdgcn_mfma_f32_16x16x32_bf16(al10, b0, acc[1][fc], 0, 0, 0);
            acc[0][fc] = __builtin_amdgcn_mfma_f32_16x16x32_bf16(al01, b1, acc[0][fc], 0, 0, 0);
            acc[1][fc] = __builtin_amdgcn_mfma_f32_16x16x32_bf16(al11, b1, acc[1][fc], 0, 0, 0);
            {
                bf16x8 b2 = *(const bf16x8*)(bp + 128 + ko0);
                acc[0][fc] = __builtin_amdgcn_mfma_f32_16x16x32_bf16(ah00, b2, acc[0][fc], 0, 0, 0);
                acc[1][fc] = __builtin_amdgcn_mfma_f32_16x16x32_bf16(ah10, b2, acc[1][fc], 0, 0, 0);
            }
            {
                bf16x8 b3 = *(const bf16x8*)(bp + 128 + ko1);
                acc[0][fc] = __builtin_amdgcn_mfma_f32_16x16x32_bf16(ah01, b3, acc[0][fc], 0, 0, 0);
                acc[1][fc] = __builtin_amdgcn_mfma_f32_16x16x32_bf16(ah11, b3, acc[1][fc], 0, 0, 0);
            }
        }

        // epilogue: u = esq/2 - dot; branchless (best, second, idx)
        #pragma unroll
        for (int fc = 0; fc < 4; ++fc) {
            int col = ct * BN + cg * 64 + fc * 16 + lan15;
            float eh = esqh_s[col];
            #pragma unroll
            for (int fr = 0; fr < 2; ++fr) {
                #pragma unroll
                for (int r = 0; r < 4; ++r) {
                    float u = eh - acc[fr][fc][r];
                    int s = fr * 4 + r;
                    second[s] = fminf(second[s], fmaxf(u, best[s]));
                    bidx[s] = (u < best[s]) ? col : bidx[s];
                    best[s] = fminf(u, best[s]);
                }
            }
        }
        __syncthreads();             // cur reads done; prefetch drained
    }

    // intra-wave reduce over 16-lane groups (lex: ties -> smaller col)
    #pragma unroll
    for (int s = 0; s < 8; ++s) {
        float b = best[s], sc = second[s];
        int bi = bidx[s];
        #pragma unroll
        for (int off = 1; off <= 8; off <<= 1) {
            float ob = __shfl_xor(b, off);
            float os = __shfl_xor(sc, off);
            int   oi = __shfl_xor(bi, off);
            float mx = fmaxf(b, ob);
            sc = fminf(fminf(sc, os), mx);
            if (ob < b) { b = ob; bi = oi; }
            else if (ob == b) bi = min(bi, oi);
        }
        best[s] = b; second[s] = sc; bidx[s] = bi;
    }
    if (lan15 == 0) {
        #pragma unroll
        for (int s = 0; s < 8; ++s) {
            int row = rg * 32 + (s >> 2) * 16 + (l >> 4) * 4 + (s & 3);
            cb_best[cg * BM + row] = best[s];
            cb_sec [cg * BM + row] = second[s];
            cb_idx [cg * BM + row] = bidx[s];
        }
    }
    __syncthreads();
    // cross-wave combine + flag emit
    if (t < BM) {
        float b0 = cb_best[t], b1 = cb_best[BM + t];
        float s0 = cb_sec[t],  s1 = cb_sec[BM + t];
        int   i0 = cb_idx[t],  i1 = cb_idx[BM + t];
        float b; int bi;
        if (b1 < b0 || (b1 == b0 && i1 < i0)) { b = b1; bi = i1; }
        else                                  { b = b0; bi = i0; }
        float sec = fminf(fminf(s0, s1), fmaxf(b0, b1));
        int gid = row0 + t;
        idx_out[gid] = (float)bi;
        bool flg = (sec - b <= EPS_U);
        fbi[t] = bi | (flg ? 0x80000000 : 0);
        unsigned long long mask = __ballot(flg);
        if (l == 0) bitmap[blockIdx.x * 2 + w] = mask;   // full-word, no init
        int nf = __popcll(mask);
        int base = 0;
        if (l == 0 && nf) base = atomicAdd(cnt, nf);
        base = __shfl(base, 0);
        if (flg) {
            int pos = __popcll(mask & ((1ull << l) - 1ull));
            int slot = base + pos;
            if (slot < SLOT_CAP) wl[slot] = gid;
        }
    }
    __syncthreads();                 // fbi visible to all waves

    // ---- fused gather tail: z_q_st rows + per-block loss partial ----
    {
        const int tk = t >> 2, qd = t & 3;
        int pk = fbi[tk];
        int bi = pk & 0x3FF;
        bool fl = pk < 0;
        const float4* zr = (const float4*)z + (size_t)(row0 + tk) * 16 + qd * 4;
        const float4* er = (const float4*)E + (size_t)bi * 16 + qd * 4;
        float4* orow = (float4*)out0 + (size_t)(row0 + tk) * 16 + qd * 4;
        float ls = 0.f;
        #pragma unroll
        for (int j = 0; j < 4; ++j) {
            float4 zv = zr[j], ev = er[j];
            float dx = ev.x - zv.x, dy = ev.y - zv.y;
            float dz = ev.z - zv.z, dw = ev.w - zv.w;
            float4 o = {zv.x + dx, zv.y + dy, zv.z + dz, zv.w + dw};
            orow[j] = o;
            ls += dx * dx + dy * dy + dz * dz + dw * dw;
        }
        if (fl) ls = 0.f;            // flagged: exact contrib comes from repair
        #pragma unroll
        for (int off = 1; off <= 32; off <<= 1) ls += __shfl_xor(ls, off);
        if (l == 0) wred[w] = ls;
    }
    __syncthreads();
    if (t == 0) {
        float s = 0.f;
        #pragma unroll
        for (int i = 0; i < 8; ++i) s += wred[i];
        partials[blockIdx.x] = s;
    }
}

// ---- K2: exact recompute, QUARTER-SPLIT (R2-pedigree staging + FMA chain)
__global__ __launch_bounds__(256) void fallback_kernel(
    const float* __restrict__ z, const float* __restrict__ E,
    const float* __restrict__ esq_g, unsigned long long* __restrict__ cand,
    const int* __restrict__ wl, const int* __restrict__ cnt_p) {
    __shared__ __align__(16) float es[DIM][128];   // 32KB [k][code]
    __shared__ __align__(16) float zl[16][72];     // padded
    __shared__ float zqs[16];

    const int t = threadIdx.x;
    const int tg = t >> 4;           // token slot 0..15
    const int cs = t & 15;           // code slice (8 codes per tile)
    const int cnt = min(*cnt_p, SLOT_CAP);
    const int nwork = ((cnt + 15) >> 4) << 2;      // chunks * 4 quarters

    for (int cb = blockIdx.x; cb < nwork; cb += 2048) {
        const int chunk = cb >> 2, qtr = cb & 3;
        const int base = chunk * 16;
        const int nval = min(16, cnt - base);
        const int tok = wl[base + (tg < nval ? tg : 0)];
        {
            float4 v = ((const float4*)z)[(size_t)tok * 16 + cs];
            *(float4*)&zl[tg][cs * 4] = v;
        }
        __syncthreads();
        if (t < 16) {                // zq per slot, sequential k (as R1)
            float s = 0.f;
            for (int k = 0; k < DIM; ++k) { float v = zl[t][k]; s += v * v; }
            zqs[t] = s;
        }
        __syncthreads();
        const float zq = zqs[tg];

        float best = 3.4e38f;
        int bi = 0;
        for (int ti = 0; ti < 2; ++ti) {         // 2 tiles of this quarter
            const int tile = qtr * 2 + ti;
            const float4* eg = (const float4*)(E + (size_t)tile * 128 * DIM);
            #pragma unroll
            for (int p = 0; p < 8; ++p) {        // R2 staging pattern verbatim
                int li = p * 256 + t;
                int c = li & 127, k4 = li >> 7;
                float4 v = eg[c * 16 + k4];
                es[k4 * 4 + 0][c] = v.x;
                es[k4 * 4 + 1][c] = v.y;
                es[k4 * 4 + 2][c] = v.z;
                es[k4 * 4 + 3][c] = v.w;
            }
            __syncthreads();

            float acc[8];
            #pragma unroll
            for (int n = 0; n < 8; ++n) acc[n] = 0.f;
            #pragma unroll 8
            for (int k = 0; k < DIM; ++k) {      // sequential fp32 FMA over K
                float a = zl[tg][k];
                float4 b0 = *(const float4*)&es[k][cs * 8 + 0];
                float4 b1 = *(const float4*)&es[k][cs * 8 + 4];
                float b[8] = {b0.x, b0.y, b0.z, b0.w, b1.x, b1.y, b1.z, b1.w};
                #pragma unroll
                for (int n = 0; n < 8; ++n) acc[n] += a * b[n];
            }
            #pragma unroll
            for (int n = 0; n < 8; ++n) {        // ascending code index, strict <
                int c = tile * 128 + cs * 8 + n;
                float d = (zq - 2.0f * acc[n]) + esq_g[c];
                if (d < best) { best = d; bi = c; }
            }
            __syncthreads();
        }
        #pragma unroll
        for (int off = 1; off <= 8; off <<= 1) {
            float ob = __shfl_xor(best, off);
            int   oi = __shfl_xor(bi, off);
            if (ob < best || (ob == best && oi < bi)) { best = ob; bi = oi; }
        }
        if (cs == 0 && tg < nval)
            cand[(size_t)(base + tg) * 4 + qtr] = packdi(best, bi);
        __syncthreads();
    }
}

// ---- K3: repair flagged tokens (u64-min of 4 quarter candidates)
__global__ __launch_bounds__(256) void repair_kernel(
    const float* __restrict__ z, const float* __restrict__ E,
    float* __restrict__ idx_out, float* __restrict__ out0,
    float* __restrict__ contrib, const unsigned long long* __restrict__ cand,
    const int* __restrict__ wl, const int* __restrict__ cnt_p) {
    const int t = threadIdx.x;
    const int tg = t >> 4;           // token slot 0..15
    const int cs = t & 15;           // float4 chunk of dim
    const int cnt = min(*cnt_p, SLOT_CAP);

    for (int s0 = blockIdx.x * 16; s0 < cnt; s0 += 512 * 16) {
        int s = s0 + tg;
        if (s < cnt) {
            int tok = wl[s];
            unsigned long long m = cand[(size_t)s * 4 + 0];
            m = min(m, cand[(size_t)s * 4 + 1]);
            m = min(m, cand[(size_t)s * 4 + 2]);
            m = min(m, cand[(size_t)s * 4 + 3]);
            int bi = (int)(unsigned)(m & 0xFFFFFFFFull);
            float4 zv = ((const float4*)z)[(size_t)tok * 16 + cs];
            float4 ev = ((const float4*)E)[(size_t)bi * 16 + cs];
            float dx = ev.x - zv.x, dy = ev.y - zv.y;
            float dz = ev.z - zv.z, dw = ev.w - zv.w;
            float4 o = {zv.x + dx, zv.y + dy, zv.z + dz, zv.w + dw};
            ((float4*)out0)[(size_t)tok * 16 + cs] = o;
            float c4 = dx * dx + dy * dy + dz * dz + dw * dw;
            #pragma unroll
            for (int off = 1; off <= 8; off <<= 1) c4 += __shfl_xor(c4, off);
            if (cs == 0) {
                idx_out[tok] = (float)bi;
                contrib[tok] = c4;
            }
        }
    }
}

// -------- K4: final loss = (sum partials + sum flagged contribs) scaled
__global__ __launch_bounds__(256) void loss_kernel(
    const float* __restrict__ partials, const unsigned long long* __restrict__ bitmap,
    const float* __restrict__ contrib, float* __restrict__ loss_out) {
    __shared__ float red[256];
    const int t = threadIdx.x;
    float p = 0.f;
    #pragma unroll
    for (int i = 0; i < 4; ++i) p += partials[t * 4 + i];
    for (int wi = t * 8; wi < t * 8 + 8; ++wi) {   // fixed token order per thread
        unsigned long long m = bitmap[wi];
        while (m) {
            int b = __builtin_ctzll(m);
            p += contrib[wi * 64 + b];
            m &= m - 1;
        }
    }
    red[t] = p;
    __syncthreads();
    for (int s = 128; s >= 1; s >>= 1) {
        if (t < s) red[t] += red[t + s];
        __syncthreads();
    }
    if (t == 0) {
        float m = red[0] / (float)(NTOK * DIM);
        loss_out[0] = m + 0.25f * m;
    }
}

extern "C" void kernel_launch(void* const* d_in, const int* in_sizes, int n_in,
                              void* d_out, int out_size, void* d_ws, size_t ws_size,
                              hipStream_t stream) {
    const float* z = (const float*)d_in[0];       // [131072, 64] f32
    const float* E = (const float*)d_in[1];       // [1024, 64] f32
    float* out = (float*)d_out;

    char* wsb = (char*)d_ws;
    float*              esq      = (float*)(wsb);               // 4 KB
    float*              esqh     = (float*)(wsb + 4096);        // 4 KB
    float*              partials = (float*)(wsb + 8192);        // 8 KB (1024 used)
    int*                cnt      = (int*)(wsb + 16384);         // 4 KB region
    int*                wl       = (int*)(wsb + 20480);         // 64 KB
    unsigned long long* bitmap   = (unsigned long long*)(wsb + 86016);  // 16 KB
    unsigned short*     Bswz     = (unsigned short*)(wsb + 102400);     // 256 KB
    float*              contrib  = (float*)(wsb + 364544);      // 512 KB
    unsigned long long* cand     = (unsigned long long*)(wsb + 888832); // 512 KB

    prep_kernel<<<256, 256, 0, stream>>>(E, Bswz, esqh, esq, cnt);
    mfma_argmin_kernel<<<NTOK / BM, 512, 0, stream>>>(z, E, Bswz, esqh,
                                                      out + IDX_OFF, out,
                                                      partials, cnt, wl, bitmap);
    fallback_kernel<<<2048, 256, 0, stream>>>(z, E, esq, cand, wl, cnt);
    repair_kernel<<<512, 256, 0, stream>>>(z, E, out + IDX_OFF, out, contrib,
                                           cand, wl, cnt);
    loss_kernel<<<1, 256, 0, stream>>>(partials, bitmap, contrib, out + LOSS_OFF);
}